// Round 12
// baseline (500.529 us; speedup 1.0000x reference)
//
#include <hip/hip_runtime.h>
#include <math.h>
#include <stdint.h>

#define N_ 8
#define T_ 512
#define V_ 32000
#define D_ 512
#define DIN_ 1024
#define H_ 8
#define HD_ 64
#define L_ 2
#define F_ 2048

typedef __attribute__((ext_vector_type(8))) short short8;
typedef __attribute__((ext_vector_type(4))) float f32x4;

__device__ __forceinline__ short f2bf(float f) {
  uint32_t u = __builtin_bit_cast(uint32_t, f);
  u = (u + 0x7FFFu + ((u >> 16) & 1u)) >> 16;
  return (short)u;
}
__device__ __forceinline__ uint32_t pack_bf2(float a, float b) {
  return (uint32_t)(uint16_t)f2bf(a) | ((uint32_t)(uint16_t)f2bf(b) << 16);
}
__device__ __forceinline__ float bflo(uint32_t u) {
  return __builtin_bit_cast(float, u << 16);
}
__device__ __forceinline__ float bfhi(uint32_t u) {
  return __builtin_bit_cast(float, u & 0xffff0000u);
}
__device__ __forceinline__ void unp8(uint4 p, float* v) {
  v[0] = bflo(p.x); v[1] = bfhi(p.x); v[2] = bflo(p.y); v[3] = bfhi(p.y);
  v[4] = bflo(p.z); v[5] = bfhi(p.z); v[6] = bflo(p.w); v[7] = bfhi(p.w);
}
// XOR-swizzled byte offset within a [row][128B] LDS tile (G4 conflict fix)
__device__ __forceinline__ int swzb(int row, int byteoff) {
  return row * 128 + (byteoff ^ ((row & 7) << 4));
}

// ============ batched transpose + f32->bf16 for ALL weights (one launch) ====
__global__ __launch_bounds__(256) void batched_transpose_kernel(
    const float* __restrict__ sa_qkv_W, const float* __restrict__ sa_o_W,
    const float* __restrict__ ff_W1, const float* __restrict__ ff_W2,
    const float* __restrict__ out_W, short* __restrict__ wq,
    short* __restrict__ wo, short* __restrict__ w1, short* __restrict__ w2,
    short* __restrict__ outWt) {
  __shared__ float tile[64][65];
  const int t = blockIdx.x;
  const float* src;
  short* dst;
  int K, N, rem;
  if (t < 384) {  // sa_qkv_W: 6 mats [512][512]
    int mat = t >> 6;
    rem = t & 63;
    K = D_; N = D_;
    src = sa_qkv_W + (size_t)mat * D_ * D_;
    dst = wq + (size_t)mat * D_ * D_;
  } else if (t < 512) {  // sa_o_W: 2 mats [512][512]
    int lt = t - 384, mat = lt >> 6;
    rem = lt & 63;
    K = D_; N = D_;
    src = sa_o_W + (size_t)mat * D_ * D_;
    dst = wo + (size_t)mat * D_ * D_;
  } else if (t < 1024) {  // ff_W1: 2 mats [512][2048]
    int lt = t - 512, mat = lt >> 8;
    rem = lt & 255;
    K = D_; N = F_;
    src = ff_W1 + (size_t)mat * D_ * F_;
    dst = w1 + (size_t)mat * F_ * D_;
  } else if (t < 1536) {  // ff_W2: 2 mats [2048][512]
    int lt = t - 1024, mat = lt >> 8;
    rem = lt & 255;
    K = F_; N = D_;
    src = ff_W2 + (size_t)mat * F_ * D_;
    dst = w2 + (size_t)mat * D_ * F_;
  } else {  // out_W: [512][32000]
    rem = t - 1536;
    K = D_; N = V_;
    src = out_W;
    dst = outWt;
  }
  const int nx = N >> 6;
  const int n0 = (rem % nx) * 64, k0 = (rem / nx) * 64;
  const int tid = threadIdx.x;
  const int c = tid & 63, r4 = tid >> 6;
#pragma unroll
  for (int i = 0; i < 16; ++i) {
    int k = r4 + i * 4;
    tile[k][c] = src[(size_t)(k0 + k) * N + n0 + c];
  }
  __syncthreads();
#pragma unroll
  for (int i = 0; i < 16; ++i) {
    int n = r4 + i * 4;
    dst[(size_t)(n0 + n) * K + k0 + c] = f2bf(tile[c][n]);
  }
}

// ============ bf16 MFMA GEMM (single-buffer m97 structure) ==================
// C[M,N] = A[M,KT](bf16) @ Bt[N,KT](bf16)^T + bias. BK=64, KT compile-time.
// ORDER 0: row-major XCD chunks; ORDER 1: bm-fast (vocab — B streamed once).
// NT: non-temporal C stores. QS: scale cols<512 by 0.125 (fold Q-scale).
template <int BM, int BN, int KT, bool RELU, bool OUTBF, bool QS, int ORDER,
          bool NT>
__global__ __launch_bounds__((BM / 64) * (BN / 64) * 64) void bf16_gemm_kernel(
    const short* __restrict__ A, const short* __restrict__ Bt,
    const float* __restrict__ bias, void* __restrict__ Cv, int M, int N) {
  constexpr int WM = BM / 64, WN = BN / 64, NW = WM * WN;
  constexpr int AISS = BM / (NW * 8), BISS = BN / (NW * 8);
  __shared__ short As[BM * 64];
  __shared__ short Bs[BN * 64];
  const int tid = threadIdx.x, lane = tid & 63, w = tid >> 6;
  const int wr = w / WN, wc = w % WN;
  const int lhi = lane >> 4, llo = lane & 15;

  const int gx = gridDim.x, gy = gridDim.y;
  const int nwg = gx * gy;
  int lin = blockIdx.y * gx + blockIdx.x;
  if ((nwg & 7) == 0) lin = (lin & 7) * (nwg >> 3) + (lin >> 3);
  int bm, bn;
  if (ORDER == 1) {
    bm = (lin % gy) * BM;
    bn = (lin / gy) * BN;
  } else {
    bm = (lin / gx) * BM;
    bn = (lin % gx) * BN;
  }

  const int arow = lane >> 3;                         // row within 8-row issue
  const int achunk = ((lane & 7) ^ (lane >> 3)) * 8;  // pre-swizzled k-chunk

  f32x4 acc[4][4];
#pragma unroll
  for (int i = 0; i < 4; ++i)
#pragma unroll
    for (int j = 0; j < 4; ++j) acc[i][j] = (f32x4)0.f;

  char* AsB = (char*)As;
  char* BsB = (char*)Bs;

  for (int k0 = 0; k0 < KT; k0 += 64) {
#pragma unroll
    for (int g = 0; g < AISS; ++g) {
      const int r0 = (w * AISS + g) * 8;
      const short* gp = A + (size_t)(bm + r0 + arow) * KT + k0 + achunk;
      __builtin_amdgcn_global_load_lds(
          (const __attribute__((address_space(1))) void*)gp,
          (__attribute__((address_space(3))) void*)&As[r0 * 64], 16, 0, 0);
    }
#pragma unroll
    for (int g = 0; g < BISS; ++g) {
      const int r0 = (w * BISS + g) * 8;
      const short* gp = Bt + (size_t)(bn + r0 + arow) * KT + k0 + achunk;
      __builtin_amdgcn_global_load_lds(
          (const __attribute__((address_space(1))) void*)gp,
          (__attribute__((address_space(3))) void*)&Bs[r0 * 64], 16, 0, 0);
    }
    __syncthreads();
#pragma unroll
    for (int ks = 0; ks < 2; ++ks) {
      short8 af[4], bf[4];
#pragma unroll
      for (int i = 0; i < 4; ++i)
        af[i] = *(const short8*)(AsB + swzb(wr * 64 + i * 16 + llo,
                                            ks * 64 + lhi * 16));
#pragma unroll
      for (int j = 0; j < 4; ++j)
        bf[j] = *(const short8*)(BsB + swzb(wc * 64 + j * 16 + llo,
                                            ks * 64 + lhi * 16));
#pragma unroll
      for (int i = 0; i < 4; ++i)
#pragma unroll
        for (int j = 0; j < 4; ++j)
          acc[i][j] = __builtin_amdgcn_mfma_f32_16x16x32_bf16(af[i], bf[j],
                                                              acc[i][j], 0, 0, 0);
    }
    __syncthreads();
  }
  // epilogue: C/D layout col=lane&15, row=(lane>>4)*4+r
#pragma unroll
  for (int j = 0; j < 4; ++j) {
    const int col = bn + wc * 64 + j * 16 + llo;
    const float bv = bias ? bias[col] : 0.f;
    const float scl = (QS && col < 512) ? 0.125f : 1.f;
#pragma unroll
    for (int i = 0; i < 4; ++i) {
      const int row0 = bm + wr * 64 + i * 16 + lhi * 4;
#pragma unroll
      for (int r = 0; r < 4; ++r) {
        float v = acc[i][j][r] + bv;
        if (RELU) v = fmaxf(v, 0.f);
        if (QS) v *= scl;
        if (OUTBF) {
          ((short*)Cv)[(size_t)(row0 + r) * N + col] = f2bf(v);
        } else if (NT) {
          __builtin_nontemporal_store(v, &((float*)Cv)[(size_t)(row0 + r) * N + col]);
        } else {
          ((float*)Cv)[(size_t)(row0 + r) * N + col] = v;
        }
      }
    }
  }
}

// ============ fallback f32 SIMT GEMM (bf16 A; only if ws too small) =========
template <int BM, int BN, int BK, int TM, int TN>
__global__ __launch_bounds__((BM / TM) * (BN / TN)) void gemm_f32_kernel(
    const short* __restrict__ A, const float* __restrict__ B,
    const float* __restrict__ bias, float* __restrict__ C, int M, int N,
    int K) {
  constexpr int THREADS = (BM / TM) * (BN / TN);
  __shared__ float As[BK][BM + 1];
  __shared__ float Bs[BK][BN + 1];
  const int tid = threadIdx.x;
  const int bm = blockIdx.y * BM, bn = blockIdx.x * BN;
  const int tcol = tid % (BN / TN), trow = tid / (BN / TN);
  float acc[TM][TN];
#pragma unroll
  for (int i = 0; i < TM; ++i)
#pragma unroll
    for (int j = 0; j < TN; ++j) acc[i][j] = 0.f;
  for (int k0 = 0; k0 < K; k0 += BK) {
    for (int i = tid; i < BM * BK; i += THREADS) {
      int m = i / BK, kk = i % BK;
      As[kk][m] = bflo((uint32_t)(uint16_t)A[(size_t)(bm + m) * K + (k0 + kk)]);
    }
    for (int i = tid; i < BK * BN; i += THREADS) {
      int kk = i / BN, n = i % BN;
      Bs[kk][n] = B[(size_t)(k0 + kk) * N + (bn + n)];
    }
    __syncthreads();
#pragma unroll
    for (int kk = 0; kk < BK; ++kk) {
      float a[TM], b[TN];
#pragma unroll
      for (int i = 0; i < TM; ++i) a[i] = As[kk][trow * TM + i];
#pragma unroll
      for (int j = 0; j < TN; ++j) b[j] = Bs[kk][tcol * TN + j];
#pragma unroll
      for (int i = 0; i < TM; ++i)
#pragma unroll
        for (int j = 0; j < TN; ++j) acc[i][j] += a[i] * b[j];
    }
    __syncthreads();
  }
#pragma unroll
  for (int i = 0; i < TM; ++i) {
    int m = bm + trow * TM + i;
#pragma unroll
    for (int j = 0; j < TN; ++j) {
      int n = bn + tcol * TN + j;
      C[(size_t)m * N + n] = acc[i][j] + (bias ? bias[n] : 0.f);
    }
  }
}

// ============ token + positional embedding (bf16 out only) ==================
__global__ __launch_bounds__(256) void embed_kernel(
    const int* __restrict__ captions, const float* __restrict__ emb,
    const float* __restrict__ pos, short* __restrict__ xb) {
  int idx4 = (blockIdx.x * 256 + threadIdx.x) * 4;  // over N*T*D
  int d = idx4 % D_;
  int nt = idx4 / D_;
  int t = nt % T_;
  int tok = captions[nt];
  float4 e = *(const float4*)(emb + (size_t)tok * D_ + d);
  float4 p = *(const float4*)(pos + (size_t)t * D_ + d);
  *(uint32_t*)(xb + idx4) = pack_bf2(e.x + p.x, e.y + p.y);
  *(uint32_t*)(xb + idx4 + 2) = pack_bf2(e.z + p.z, e.w + p.w);
}

// ============ tiny-M matmul: one wave per output element, lanes split K =====
__global__ __launch_bounds__(256) void wave_mm_kernel(
    const float* __restrict__ A, const float* __restrict__ W,
    const float* __restrict__ bias, float* __restrict__ out, int M, int K,
    int N) {
  const int widx = blockIdx.x * 4 + (threadIdx.x >> 6);
  const int lane = threadIdx.x & 63;
  if (widx >= M * N) return;
  const int m = widx / N, n = widx % N;
  const float* a = A + (size_t)m * K;
  const float* w = W + n;
  float s = 0.f;
  for (int k = lane; k < K; k += 64) s += a[k] * w[(size_t)k * N];
#pragma unroll
  for (int off = 32; off; off >>= 1) s += __shfl_xor(s, off);
  if (lane == 0) out[widx] = s + (bias ? bias[n] : 0.f);
}

// ============ layer-batched tiny matmul for the CA chain ====================
__global__ __launch_bounds__(256) void ca_mm_kernel(
    const float* __restrict__ A, size_t a_lstride, const float* __restrict__ W,
    size_t w_lstride, const float* __restrict__ bias, size_t b_lstride,
    float* __restrict__ out, int M, int K, int N) {
  const int widx = blockIdx.x * 4 + (threadIdx.x >> 6);
  const int lane = threadIdx.x & 63;
  if (widx >= L_ * M * N) return;
  const int l = widx / (M * N);
  const int r = widx % (M * N);
  const int m = r / N, n = r % N;
  const float* a = A + l * a_lstride + (size_t)m * K;
  const float* w = W + l * w_lstride + n;
  float s = 0.f;
  for (int k = lane; k < K; k += 64) s += a[k] * w[(size_t)k * N];
#pragma unroll
  for (int off = 32; off; off >>= 1) s += __shfl_xor(s, off);
  if (lane == 0) out[widx] = s + bias[l * b_lstride + n];
}

// ============ MFMA flash attention, work-balanced grid + defer-max ==========
// Q pre-scaled by 1/8 in the qkv GEMM epilogue (exact: exponent shift).
__global__ __launch_bounds__(256) void flash_attn_kernel(
    const short* __restrict__ qkv, short* __restrict__ y) {
  __shared__ short Ks[2][64 * 64];  // [s][d] bf16, swizzled
  __shared__ short Vt[2][64 * 64];  // [d][s] bf16, swizzled
  __shared__ short Ps[4][16 * 64];  // per-wave [t][s] bf16, swizzled
  const int b = blockIdx.x;
  const int pair = b & 255, half = b >> 8;
  const int n = pair >> 5;        // 0..7
  const int h = (pair >> 2) & 7;  // 0..7
  const int tp = pair & 3;        // 0..3
  const int tile = half ? 7 - tp : tp;
  const int t0 = tile * 64;
  const int tid = threadIdx.x, lane = tid & 63, w = tid >> 6;
  const int lhi = lane >> 4, llo = lane & 15;
  char* PsB = (char*)Ps[w];

  const short* qrow = qkv + (size_t)(n * T_ + t0 + w * 16 + llo) * 1536 + h * 64;
  short8 qf[2];
#pragma unroll
  for (int kc = 0; kc < 2; ++kc) qf[kc] = *(const short8*)(qrow + kc * 32 + lhi * 8);

  float m = -1e30f, l = 0.f;
  f32x4 acc[4];
#pragma unroll
  for (int dc = 0; dc < 4; ++dc) acc[dc] = (f32x4)0.f;

  const int arow = lane >> 3;
  const int achunk = ((lane & 7) ^ (lane >> 3)) * 8;  // pre-swizzled chunk
  const int vr = tid >> 2, vd0 = (tid & 3) * 16;      // V-stage assignment
  const int tg = t0 + w * 16 + llo;

  auto stageK = [&](int buf, int s0) {
#pragma unroll
    for (int g = 0; g < 2; ++g) {
      const int r0 = w * 16 + g * 8;
      const short* gp =
          qkv + (size_t)(n * T_ + s0 + r0 + arow) * 1536 + 512 + h * 64 + achunk;
      __builtin_amdgcn_global_load_lds(
          (const __attribute__((address_space(1))) void*)gp,
          (__attribute__((address_space(3))) void*)&Ks[buf][r0 * 64], 16, 0, 0);
    }
  };
  auto loadV = [&](int s0, short8& a, short8& bb) {
    const short* vg = qkv + (size_t)(n * T_ + s0 + vr) * 1536 + 1024 + h * 64 + vd0;
    a = *(const short8*)(vg);
    bb = *(const short8*)(vg + 8);
  };
  auto scatterV = [&](int buf, const short8& a, const short8& bb) {
    char* VtB = (char*)Vt[buf];
#pragma unroll
    for (int j = 0; j < 8; ++j) {
      *(short*)(VtB + swzb(vd0 + j, vr * 2)) = a[j];
      *(short*)(VtB + swzb(vd0 + 8 + j, vr * 2)) = bb[j];
    }
  };

  const int nchunk = tile + 1;
  {
    short8 va, vb;
    stageK(0, 0);
    loadV(0, va, vb);
    scatterV(0, va, vb);
  }
  __syncthreads();

  for (int c = 0; c < nchunk; ++c) {
    const int cur = c & 1;
    const int s0 = c * 64;
    short8 va, vb;
    const bool nxt = (c + 1 < nchunk);
    if (nxt) {  // T14: issue-early
      stageK(cur ^ 1, s0 + 64);
      loadV(s0 + 64, va, vb);
    }
    char* KsB = (char*)Ks[cur];
    char* VtB = (char*)Vt[cur];

    f32x4 st[4];
    __builtin_amdgcn_s_setprio(1);
#pragma unroll
    for (int tle = 0; tle < 4; ++tle) {
      st[tle] = (f32x4)0.f;
#pragma unroll
      for (int kc = 0; kc < 2; ++kc) {
        short8 kf =
            *(const short8*)(KsB + swzb(tle * 16 + llo, kc * 64 + lhi * 16));
        st[tle] =
            __builtin_amdgcn_mfma_f32_16x16x32_bf16(kf, qf[kc], st[tle], 0, 0, 0);
      }
    }
    __builtin_amdgcn_s_setprio(0);
    if (s0 == t0) {  // diagonal chunk: causal mask
#pragma unroll
      for (int tle = 0; tle < 4; ++tle)
#pragma unroll
        for (int r = 0; r < 4; ++r)
          if (s0 + tle * 16 + lhi * 4 + r > tg) st[tle][r] = -1e30f;
    }
    float cmax = -1e30f;
#pragma unroll
    for (int tle = 0; tle < 4; ++tle)
#pragma unroll
      for (int r = 0; r < 4; ++r) cmax = fmaxf(cmax, st[tle][r]);
    cmax = fmaxf(cmax, __shfl_xor(cmax, 16));
    cmax = fmaxf(cmax, __shfl_xor(cmax, 32));
    // T13 defer-max: skip O-rescale when chunk max grew by <= 8 (P <= e^8)
    const bool skip = __all(cmax - m <= 8.f);
    float mn = skip ? m : fmaxf(m, cmax);
    float lsum = 0.f;
#pragma unroll
    for (int tle = 0; tle < 4; ++tle)
#pragma unroll
      for (int r = 0; r < 4; ++r) {
        float p = __expf(st[tle][r] - mn);
        st[tle][r] = p;
        lsum += p;
      }
    lsum += __shfl_xor(lsum, 16);
    lsum += __shfl_xor(lsum, 32);
#pragma unroll
    for (int tle = 0; tle < 4; ++tle) {
      int base = swzb(llo, tle * 32 + lhi * 8);
      *(uint32_t*)(PsB + base) = pack_bf2(st[tle][0], st[tle][1]);
      *(uint32_t*)(PsB + base + 4) = pack_bf2(st[tle][2], st[tle][3]);
    }
    if (skip) {
      l = l + lsum;
    } else {
      float corr = __expf(m - mn);
      l = l * corr + lsum;
      m = mn;
      float c0 = __shfl(corr, lhi * 4 + 0), c1 = __shfl(corr, lhi * 4 + 1);
      float c2 = __shfl(corr, lhi * 4 + 2), c3 = __shfl(corr, lhi * 4 + 3);
#pragma unroll
      for (int dc = 0; dc < 4; ++dc) {
        acc[dc][0] *= c0;
        acc[dc][1] *= c1;
        acc[dc][2] *= c2;
        acc[dc][3] *= c3;
      }
    }
    short8 pf0 = *(const short8*)(PsB + swzb(llo, lhi * 16));
    short8 pf1 = *(const short8*)(PsB + swzb(llo, 64 + lhi * 16));
    __builtin_amdgcn_s_setprio(1);
#pragma unroll
    for (int dc = 0; dc < 4; ++dc) {
      short8 vf0 = *(const short8*)(VtB + swzb(dc * 16 + llo, lhi * 16));
      short8 vf1 = *(const short8*)(VtB + swzb(dc * 16 + llo, 64 + lhi * 16));
      acc[dc] = __builtin_amdgcn_mfma_f32_16x16x32_bf16(pf0, vf0, acc[dc], 0, 0, 0);
      acc[dc] = __builtin_amdgcn_mfma_f32_16x16x32_bf16(pf1, vf1, acc[dc], 0, 0, 0);
    }
    __builtin_amdgcn_s_setprio(0);
    if (nxt) scatterV(cur ^ 1, va, vb);  // T14: write-late (other buffer)
    __syncthreads();
  }

  float linv = 1.f / l;
  float l0 = __shfl(linv, lhi * 4 + 0), l1 = __shfl(linv, lhi * 4 + 1);
  float l2 = __shfl(linv, lhi * 4 + 2), l3 = __shfl(linv, lhi * 4 + 3);
  short* yb = y + (size_t)(n * T_ + t0 + w * 16) * D_ + h * 64;
#pragma unroll
  for (int dc = 0; dc < 4; ++dc) {
    yb[(size_t)(lhi * 4 + 0) * D_ + dc * 16 + llo] = f2bf(acc[dc][0] * l0);
    yb[(size_t)(lhi * 4 + 1) * D_ + dc * 16 + llo] = f2bf(acc[dc][1] * l1);
    yb[(size_t)(lhi * 4 + 2) * D_ + dc * 16 + llo] = f2bf(acc[dc][2] * l2);
    yb[(size_t)(lhi * 4 + 3) * D_ + dc * 16 + llo] = f2bf(acc[dc][3] * l3);
  }
}

// ============ wave-per-row LN: block = 4 waves = 4 rows, no barriers ========
__global__ __launch_bounds__(256) void ln_res_kernel(
    short* __restrict__ xb, const short* __restrict__ res,
    const float* __restrict__ g, const float* __restrict__ b) {
  const int row = blockIdx.x * 4 + (threadIdx.x >> 6);
  const int lane = threadIdx.x & 63;
  const int d0 = lane * 8;
  uint4 xp = *(const uint4*)(xb + (size_t)row * D_ + d0);
  uint4 rp = *(const uint4*)(res + (size_t)row * D_ + d0);
  float xv[8], rv[8], v[8];
  unp8(xp, xv);
  unp8(rp, rv);
  float s = 0.f, sq = 0.f;
#pragma unroll
  for (int i = 0; i < 8; ++i) {
    v[i] = xv[i] + rv[i];
    s += v[i];
    sq += v[i] * v[i];
  }
#pragma unroll
  for (int off = 32; off; off >>= 1) {
    s += __shfl_xor(s, off);
    sq += __shfl_xor(sq, off);
  }
  float mu = s * (1.f / D_);
  float var = sq * (1.f / D_) - mu * mu;
  float r = rsqrtf(var + 1e-5f);
  float4 g0 = *(const float4*)(g + d0), g1 = *(const float4*)(g + d0 + 4);
  float4 b0 = *(const float4*)(b + d0), b1 = *(const float4*)(b + d0 + 4);
  float gg[8] = {g0.x, g0.y, g0.z, g0.w, g1.x, g1.y, g1.z, g1.w};
  float bb[8] = {b0.x, b0.y, b0.z, b0.w, b1.x, b1.y, b1.z, b1.w};
  float o[8];
#pragma unroll
  for (int i = 0; i < 8; ++i) o[i] = (v[i] - mu) * r * gg[i] + bb[i];
  uint4 op = {pack_bf2(o[0], o[1]), pack_bf2(o[2], o[3]),
              pack_bf2(o[4], o[5]), pack_bf2(o[6], o[7])};
  *(uint4*)(xb + (size_t)row * D_ + d0) = op;
}

// ============ wave-per-row DOUBLE LN: xb = LN2(LN1(xb+res) + oc[row/T]) =====
__global__ __launch_bounds__(256) void ln2_res_kernel(
    short* __restrict__ xb, const short* __restrict__ res,
    const float* __restrict__ oc, const float* __restrict__ g1,
    const float* __restrict__ b1, const float* __restrict__ g2,
    const float* __restrict__ b2) {
  const int row = blockIdx.x * 4 + (threadIdx.x >> 6);
  const int lane = threadIdx.x & 63;
  const int d0 = lane * 8;
  uint4 xp = *(const uint4*)(xb + (size_t)row * D_ + d0);
  uint4 rp = *(const uint4*)(res + (size_t)row * D_ + d0);
  float xv[8], rv[8], v[8];
  unp8(xp, xv);
  unp8(rp, rv);
  float s = 0.f, sq = 0.f;
#pragma unroll
  for (int i = 0; i < 8; ++i) {
    v[i] = xv[i] + rv[i];
    s += v[i];
    sq += v[i] * v[i];
  }
#pragma unroll
  for (int off = 32; off; off >>= 1) {
    s += __shfl_xor(s, off);
    sq += __shfl_xor(sq, off);
  }
  float mu = s * (1.f / D_);
  float var = sq * (1.f / D_) - mu * mu;
  float r = rsqrtf(var + 1e-5f);
  float4 ga = *(const float4*)(g1 + d0), gb = *(const float4*)(g1 + d0 + 4);
  float4 ba = *(const float4*)(b1 + d0), bbv = *(const float4*)(b1 + d0 + 4);
  const float* ocr = oc + (size_t)(row / T_) * D_ + d0;
  float4 oa = *(const float4*)(ocr), ob = *(const float4*)(ocr + 4);
  float g1v[8] = {ga.x, ga.y, ga.z, ga.w, gb.x, gb.y, gb.z, gb.w};
  float b1v[8] = {ba.x, ba.y, ba.z, ba.w, bbv.x, bbv.y, bbv.z, bbv.w};
  float ov[8] = {oa.x, oa.y, oa.z, oa.w, ob.x, ob.y, ob.z, ob.w};
  float u[8];
  float s2 = 0.f, sq2 = 0.f;
#pragma unroll
  for (int i = 0; i < 8; ++i) {
    u[i] = (v[i] - mu) * r * g1v[i] + b1v[i] + ov[i];
    s2 += u[i];
    sq2 += u[i] * u[i];
  }
#pragma unroll
  for (int off = 32; off; off >>= 1) {
    s2 += __shfl_xor(s2, off);
    sq2 += __shfl_xor(sq2, off);
  }
  float mu2 = s2 * (1.f / D_);
  float var2 = sq2 * (1.f / D_) - mu2 * mu2;
  float r2 = rsqrtf(var2 + 1e-5f);
  float4 gc = *(const float4*)(g2 + d0), gd = *(const float4*)(g2 + d0 + 4);
  float4 bc = *(const float4*)(b2 + d0), bd = *(const float4*)(b2 + d0 + 4);
  float g2v[8] = {gc.x, gc.y, gc.z, gc.w, gd.x, gd.y, gd.z, gd.w};
  float b2v[8] = {bc.x, bc.y, bc.z, bc.w, bd.x, bd.y, bd.z, bd.w};
  float o[8];
#pragma unroll
  for (int i = 0; i < 8; ++i) o[i] = (u[i] - mu2) * r2 * g2v[i] + b2v[i];
  uint4 op = {pack_bf2(o[0], o[1]), pack_bf2(o[2], o[3]),
              pack_bf2(o[4], o[5]), pack_bf2(o[6], o[7])};
  *(uint4*)(xb + (size_t)row * D_ + d0) = op;
}

// ============ host orchestration ============================================
extern "C" void kernel_launch(void* const* d_in, const int* in_sizes, int n_in,
                              void* d_out, int out_size, void* d_ws,
                              size_t ws_size, hipStream_t stream) {
  const float* features = (const float*)d_in[0];
  const int* captions = (const int*)d_in[1];
  const float* emb_table = (const float*)d_in[2];
  const float* pos_table = (const float*)d_in[3];
  const float* feat_W = (const float*)d_in[4];
  const float* feat_b = (const float*)d_in[5];
  const float* sa_qkv_W = (const float*)d_in[6];
  const float* sa_qkv_b = (const float*)d_in[7];
  const float* sa_o_W = (const float*)d_in[8];
  const float* sa_o_b = (const float*)d_in[9];
  const float* sa_ln = (const float*)d_in[10];
  const float* ca_qkv_W = (const float*)d_in[11];
  const float* ca_qkv_b = (const float*)d_in[12];
  const float* ca_o_W = (const float*)d_in[13];
  const float* ca_o_b = (const float*)d_in[14];
  const float* ca_ln = (const float*)d_in[15];
  const float* ff_W1 = (const float*)d_in[16];
  const float* ff_b1 = (const float*)d_in[17];
  const float* ff_W2 = (const float*)d_in[18];
  const float* ff_b2 = (const float*)d_in[19];
  const float* ff_ln = (const float*)d_in[20];
  const float* out_W = (const float*)d_in[21];
  const float* out_b = (const float*)d_in[22];

  const int ROWS = N_ * T_;  // 4096
  float* out = (float*)d_out;

  // ---- ws scratch ---------------------------------------------------------
  short* xb = (short*)d_ws;  // ROWS*D bf16 (residual stream)
  float* cond = (float*)(xb + (size_t)ROWS * D_);
  float* vcAll = cond + N_ * D_;                // [L][N][D]
  float* ocAll = vcAll + (size_t)L_ * N_ * D_;  // [L][N][D]
  short* outWt = (short*)(ocAll + (size_t)L_ * N_ * D_);
  size_t ws_need = (size_t)ROWS * D_ * 2 + (1 + 2 * L_) * N_ * D_ * 4 +
                   (size_t)V_ * D_ * 2;
  const bool big_ws = ws_size >= ws_need;

  // ---- d_out scratch (consumed before the final GEMM overwrites) ----------
  short* qkvb = (short*)out;                  // ROWS*1536 bf16
  short* yb = qkvb + (size_t)ROWS * 3 * D_;   // ROWS*D bf16
  short* ffhb = yb + (size_t)ROWS * D_;       // ROWS*F bf16
  short* tmpb = ffhb + (size_t)ROWS * F_;     // ROWS*D bf16
  short* wq = tmpb + (size_t)ROWS * D_;       // L*3*D rows of [D]
  short* wo = wq + (size_t)L_ * 3 * D_ * D_;  // L*D rows of [D]
  short* w1 = wo + (size_t)L_ * D_ * D_;      // L*F rows of [D]
  short* w2 = w1 + (size_t)L_ * F_ * D_;      // L*D rows of [F]

  // ---- ALL weight transposes in one launch --------------------------------
  hipLaunchKernelGGL(batched_transpose_kernel, dim3(big_ws ? 5536 : 1536),
                     dim3(256), 0, stream, sa_qkv_W, sa_o_W, ff_W1, ff_W2,
                     out_W, wq, wo, w1, w2, outWt);

  // ---- cond + CA chain (layer-batched wave matmuls) + embedding -----------
  hipLaunchKernelGGL(wave_mm_kernel, dim3((N_ * D_ + 3) / 4), dim3(256), 0,
                     stream, features, feat_W, feat_b, cond, N_, DIN_, D_);
  hipLaunchKernelGGL(ca_mm_kernel, dim3((L_ * N_ * D_ + 3) / 4), dim3(256), 0,
                     stream, cond, (size_t)0, ca_qkv_W + (size_t)2 * D_ * D_,
                     (size_t)3 * D_ * D_, ca_qkv_b + 2 * D_, (size_t)3 * D_,
                     vcAll, N_, D_, D_);
  hipLaunchKernelGGL(ca_mm_kernel, dim3((L_ * N_ * D_ + 3) / 4), dim3(256), 0,
                     stream, vcAll, (size_t)N_ * D_, ca_o_W, (size_t)D_ * D_,
                     ca_o_b, (size_t)D_, ocAll, N_, D_, D_);
  hipLaunchKernelGGL(embed_kernel, dim3(ROWS * D_ / 1024), dim3(256), 0, stream,
                     captions, emb_table, pos_table, xb);

  for (int l = 0; l < L_; ++l) {
    // fused QKV projection (Q pre-scaled by 1/8 in epilogue) -> bf16
    hipLaunchKernelGGL(
        (bf16_gemm_kernel<128, 128, 512, false, true, true, 0, false>),
        dim3(3 * D_ / 128, ROWS / 128), dim3(256), 0, stream, xb,
        wq + (size_t)l * 3 * D_ * D_, sa_qkv_b + (size_t)l * 3 * D_, qkvb,
        ROWS, 3 * D_);
    hipLaunchKernelGGL(flash_attn_kernel, dim3(512), dim3(256), 0, stream,
                       qkvb, yb);
    // attn out projection (N=512, full-coverage 64x128 tile) -> bf16 tmp
    hipLaunchKernelGGL(
        (bf16_gemm_kernel<64, 128, 512, false, true, false, 0, false>),
        dim3(D_ / 128, ROWS / 64), dim3(128), 0, stream, yb,
        wo + (size_t)l * D_ * D_, sa_o_b + (size_t)l * D_, tmpb, ROWS, D_);
    // fused sa-LN + ca-residual + ca-LN (wave-per-row)
    hipLaunchKernelGGL(ln2_res_kernel, dim3(ROWS / 4), dim3(256), 0, stream,
                       xb, tmpb, ocAll + (size_t)l * N_ * D_,
                       sa_ln + (size_t)l * 2 * D_,
                       sa_ln + (size_t)l * 2 * D_ + D_,
                       ca_ln + (size_t)l * 2 * D_,
                       ca_ln + (size_t)l * 2 * D_ + D_);

    // FFN
    hipLaunchKernelGGL(
        (bf16_gemm_kernel<128, 128, 512, true, true, false, 0, false>),
        dim3(F_ / 128, ROWS / 128), dim3(256), 0, stream, xb,
        w1 + (size_t)l * F_ * D_, ff_b1 + (size_t)l * F_, ffhb, ROWS, F_);
    hipLaunchKernelGGL(
        (bf16_gemm_kernel<64, 128, 2048, false, true, false, 0, false>),
        dim3(D_ / 128, ROWS / 64), dim3(128), 0, stream, ffhb,
        w2 + (size_t)l * D_ * F_, ff_b2 + (size_t)l * D_, tmpb, ROWS, D_);
    hipLaunchKernelGGL(ln_res_kernel, dim3(ROWS / 4), dim3(256), 0, stream, xb,
                       tmpb, ff_ln + (size_t)l * 2 * D_,
                       ff_ln + (size_t)l * 2 * D_ + D_);
  }

  // ---- final vocab projection: 128^2 tile, bm-fast XCD order, NT stores ---
  if (big_ws) {
    hipLaunchKernelGGL(
        (bf16_gemm_kernel<128, 128, 512, false, false, false, 1, true>),
        dim3(V_ / 128, ROWS / 128), dim3(256), 0, stream, xb, outWt, out_b,
        out, ROWS, V_);
  } else {
    dim3 grid(V_ / 64, ROWS / 128);
    hipLaunchKernelGGL((gemm_f32_kernel<128, 64, 16, 8, 4>), grid, dim3(256), 0,
                       stream, xb, out_W, out_b, out, ROWS, V_, D_);
  }
}

// Round 13
// 471.837 us; speedup vs baseline: 1.0608x; 1.0608x over previous
//
#include <hip/hip_runtime.h>
#include <math.h>
#include <stdint.h>

#define N_ 8
#define T_ 512
#define V_ 32000
#define D_ 512
#define DIN_ 1024
#define H_ 8
#define HD_ 64
#define L_ 2
#define F_ 2048

typedef __attribute__((ext_vector_type(8))) short short8;
typedef __attribute__((ext_vector_type(4))) float f32x4;

__device__ __forceinline__ short f2bf(float f) {
  uint32_t u = __builtin_bit_cast(uint32_t, f);
  u = (u + 0x7FFFu + ((u >> 16) & 1u)) >> 16;
  return (short)u;
}
__device__ __forceinline__ uint32_t pack_bf2(float a, float b) {
  return (uint32_t)(uint16_t)f2bf(a) | ((uint32_t)(uint16_t)f2bf(b) << 16);
}
__device__ __forceinline__ float bflo(uint32_t u) {
  return __builtin_bit_cast(float, u << 16);
}
__device__ __forceinline__ float bfhi(uint32_t u) {
  return __builtin_bit_cast(float, u & 0xffff0000u);
}
__device__ __forceinline__ void unp8(uint4 p, float* v) {
  v[0] = bflo(p.x); v[1] = bfhi(p.x); v[2] = bflo(p.y); v[3] = bfhi(p.y);
  v[4] = bflo(p.z); v[5] = bfhi(p.z); v[6] = bflo(p.w); v[7] = bfhi(p.w);
}
// XOR-swizzled byte offset within a [row][128B] LDS tile (G4 conflict fix)
__device__ __forceinline__ int swzb(int row, int byteoff) {
  return row * 128 + (byteoff ^ ((row & 7) << 4));
}

// ============ batched transpose + f32->bf16 for ALL weights (one launch) ====
__global__ __launch_bounds__(256) void batched_transpose_kernel(
    const float* __restrict__ sa_qkv_W, const float* __restrict__ sa_o_W,
    const float* __restrict__ ff_W1, const float* __restrict__ ff_W2,
    const float* __restrict__ out_W, short* __restrict__ wq,
    short* __restrict__ wo, short* __restrict__ w1, short* __restrict__ w2,
    short* __restrict__ outWt) {
  __shared__ float tile[64][65];
  const int t = blockIdx.x;
  const float* src;
  short* dst;
  int K, N, rem;
  if (t < 384) {  // sa_qkv_W: 6 mats [512][512]
    int mat = t >> 6;
    rem = t & 63;
    K = D_; N = D_;
    src = sa_qkv_W + (size_t)mat * D_ * D_;
    dst = wq + (size_t)mat * D_ * D_;
  } else if (t < 512) {  // sa_o_W: 2 mats [512][512]
    int lt = t - 384, mat = lt >> 6;
    rem = lt & 63;
    K = D_; N = D_;
    src = sa_o_W + (size_t)mat * D_ * D_;
    dst = wo + (size_t)mat * D_ * D_;
  } else if (t < 1024) {  // ff_W1: 2 mats [512][2048]
    int lt = t - 512, mat = lt >> 8;
    rem = lt & 255;
    K = D_; N = F_;
    src = ff_W1 + (size_t)mat * D_ * F_;
    dst = w1 + (size_t)mat * F_ * D_;
  } else if (t < 1536) {  // ff_W2: 2 mats [2048][512]
    int lt = t - 1024, mat = lt >> 8;
    rem = lt & 255;
    K = F_; N = D_;
    src = ff_W2 + (size_t)mat * F_ * D_;
    dst = w2 + (size_t)mat * D_ * F_;
  } else {  // out_W: [512][32000]
    rem = t - 1536;
    K = D_; N = V_;
    src = out_W;
    dst = outWt;
  }
  const int nx = N >> 6;
  const int n0 = (rem % nx) * 64, k0 = (rem / nx) * 64;
  const int tid = threadIdx.x;
  const int c = tid & 63, r4 = tid >> 6;
#pragma unroll
  for (int i = 0; i < 16; ++i) {
    int k = r4 + i * 4;
    tile[k][c] = src[(size_t)(k0 + k) * N + n0 + c];
  }
  __syncthreads();
#pragma unroll
  for (int i = 0; i < 16; ++i) {
    int n = r4 + i * 4;
    dst[(size_t)(n0 + n) * K + k0 + c] = f2bf(tile[c][n]);
  }
}

// ============ bf16 MFMA GEMM (single-buffer m97 structure, runtime K) =======
// C[M,N] = A[M,K](bf16) @ Bt[N,K](bf16)^T + bias. BK=64.
// ORDER 0: row-major XCD chunks; ORDER 1: bm-fast (vocab — B streamed once).
// NT: non-temporal C stores. QS: scale cols<512 by 0.125 (fold Q-scale).
template <int BM, int BN, bool RELU, bool OUTBF, bool QS, int ORDER, bool NT>
__global__ __launch_bounds__((BM / 64) * (BN / 64) * 64) void bf16_gemm_kernel(
    const short* __restrict__ A, const short* __restrict__ Bt,
    const float* __restrict__ bias, void* __restrict__ Cv, int M, int N,
    int K) {
  constexpr int WM = BM / 64, WN = BN / 64, NW = WM * WN;
  constexpr int AISS = BM / (NW * 8), BISS = BN / (NW * 8);
  __shared__ short As[BM * 64];
  __shared__ short Bs[BN * 64];
  const int tid = threadIdx.x, lane = tid & 63, w = tid >> 6;
  const int wr = w / WN, wc = w % WN;
  const int lhi = lane >> 4, llo = lane & 15;

  const int gx = gridDim.x, gy = gridDim.y;
  const int nwg = gx * gy;
  int lin = blockIdx.y * gx + blockIdx.x;
  if ((nwg & 7) == 0) lin = (lin & 7) * (nwg >> 3) + (lin >> 3);
  int bm, bn;
  if (ORDER == 1) {
    bm = (lin % gy) * BM;
    bn = (lin / gy) * BN;
  } else {
    bm = (lin / gx) * BM;
    bn = (lin % gx) * BN;
  }

  const int arow = lane >> 3;                         // row within 8-row issue
  const int achunk = ((lane & 7) ^ (lane >> 3)) * 8;  // pre-swizzled k-chunk

  f32x4 acc[4][4];
#pragma unroll
  for (int i = 0; i < 4; ++i)
#pragma unroll
    for (int j = 0; j < 4; ++j) acc[i][j] = (f32x4)0.f;

  char* AsB = (char*)As;
  char* BsB = (char*)Bs;

  for (int k0 = 0; k0 < K; k0 += 64) {
#pragma unroll
    for (int g = 0; g < AISS; ++g) {
      const int r0 = (w * AISS + g) * 8;
      const short* gp = A + (size_t)(bm + r0 + arow) * K + k0 + achunk;
      __builtin_amdgcn_global_load_lds(
          (const __attribute__((address_space(1))) void*)gp,
          (__attribute__((address_space(3))) void*)&As[r0 * 64], 16, 0, 0);
    }
#pragma unroll
    for (int g = 0; g < BISS; ++g) {
      const int r0 = (w * BISS + g) * 8;
      const short* gp = Bt + (size_t)(bn + r0 + arow) * K + k0 + achunk;
      __builtin_amdgcn_global_load_lds(
          (const __attribute__((address_space(1))) void*)gp,
          (__attribute__((address_space(3))) void*)&Bs[r0 * 64], 16, 0, 0);
    }
    __syncthreads();
#pragma unroll
    for (int ks = 0; ks < 2; ++ks) {
      short8 af[4], bf[4];
#pragma unroll
      for (int i = 0; i < 4; ++i)
        af[i] = *(const short8*)(AsB + swzb(wr * 64 + i * 16 + llo,
                                            ks * 64 + lhi * 16));
#pragma unroll
      for (int j = 0; j < 4; ++j)
        bf[j] = *(const short8*)(BsB + swzb(wc * 64 + j * 16 + llo,
                                            ks * 64 + lhi * 16));
#pragma unroll
      for (int i = 0; i < 4; ++i)
#pragma unroll
        for (int j = 0; j < 4; ++j)
          acc[i][j] = __builtin_amdgcn_mfma_f32_16x16x32_bf16(af[i], bf[j],
                                                              acc[i][j], 0, 0, 0);
    }
    __syncthreads();
  }
  // epilogue: C/D layout col=lane&15, row=(lane>>4)*4+r
#pragma unroll
  for (int j = 0; j < 4; ++j) {
    const int col = bn + wc * 64 + j * 16 + llo;
    const float bv = bias ? bias[col] : 0.f;
    const float scl = (QS && col < 512) ? 0.125f : 1.f;
#pragma unroll
    for (int i = 0; i < 4; ++i) {
      const int row0 = bm + wr * 64 + i * 16 + lhi * 4;
#pragma unroll
      for (int r = 0; r < 4; ++r) {
        float v = acc[i][j][r] + bv;
        if (RELU) v = fmaxf(v, 0.f);
        if (QS) v *= scl;
        if (OUTBF) {
          ((short*)Cv)[(size_t)(row0 + r) * N + col] = f2bf(v);
        } else if (NT) {
          __builtin_nontemporal_store(v, &((float*)Cv)[(size_t)(row0 + r) * N + col]);
        } else {
          ((float*)Cv)[(size_t)(row0 + r) * N + col] = v;
        }
      }
    }
  }
}

// ============ fallback f32 SIMT GEMM (bf16 A; only if ws too small) =========
template <int BM, int BN, int BK, int TM, int TN>
__global__ __launch_bounds__((BM / TM) * (BN / TN)) void gemm_f32_kernel(
    const short* __restrict__ A, const float* __restrict__ B,
    const float* __restrict__ bias, float* __restrict__ C, int M, int N,
    int K) {
  constexpr int THREADS = (BM / TM) * (BN / TN);
  __shared__ float As[BK][BM + 1];
  __shared__ float Bs[BK][BN + 1];
  const int tid = threadIdx.x;
  const int bm = blockIdx.y * BM, bn = blockIdx.x * BN;
  const int tcol = tid % (BN / TN), trow = tid / (BN / TN);
  float acc[TM][TN];
#pragma unroll
  for (int i = 0; i < TM; ++i)
#pragma unroll
    for (int j = 0; j < TN; ++j) acc[i][j] = 0.f;
  for (int k0 = 0; k0 < K; k0 += BK) {
    for (int i = tid; i < BM * BK; i += THREADS) {
      int m = i / BK, kk = i % BK;
      As[kk][m] = bflo((uint32_t)(uint16_t)A[(size_t)(bm + m) * K + (k0 + kk)]);
    }
    for (int i = tid; i < BK * BN; i += THREADS) {
      int kk = i / BN, n = i % BN;
      Bs[kk][n] = B[(size_t)(k0 + kk) * N + (bn + n)];
    }
    __syncthreads();
#pragma unroll
    for (int kk = 0; kk < BK; ++kk) {
      float a[TM], b[TN];
#pragma unroll
      for (int i = 0; i < TM; ++i) a[i] = As[kk][trow * TM + i];
#pragma unroll
      for (int j = 0; j < TN; ++j) b[j] = Bs[kk][tcol * TN + j];
#pragma unroll
      for (int i = 0; i < TM; ++i)
#pragma unroll
        for (int j = 0; j < TN; ++j) acc[i][j] += a[i] * b[j];
    }
    __syncthreads();
  }
#pragma unroll
  for (int i = 0; i < TM; ++i) {
    int m = bm + trow * TM + i;
#pragma unroll
    for (int j = 0; j < TN; ++j) {
      int n = bn + tcol * TN + j;
      C[(size_t)m * N + n] = acc[i][j] + (bias ? bias[n] : 0.f);
    }
  }
}

// ============ token + positional embedding (bf16 out only) ==================
__global__ __launch_bounds__(256) void embed_kernel(
    const int* __restrict__ captions, const float* __restrict__ emb,
    const float* __restrict__ pos, short* __restrict__ xb) {
  int idx4 = (blockIdx.x * 256 + threadIdx.x) * 4;  // over N*T*D
  int d = idx4 % D_;
  int nt = idx4 / D_;
  int t = nt % T_;
  int tok = captions[nt];
  float4 e = *(const float4*)(emb + (size_t)tok * D_ + d);
  float4 p = *(const float4*)(pos + (size_t)t * D_ + d);
  *(uint32_t*)(xb + idx4) = pack_bf2(e.x + p.x, e.y + p.y);
  *(uint32_t*)(xb + idx4 + 2) = pack_bf2(e.z + p.z, e.w + p.w);
}

// ============ tiny-M matmul: one wave per output element, lanes split K =====
__global__ __launch_bounds__(256) void wave_mm_kernel(
    const float* __restrict__ A, const float* __restrict__ W,
    const float* __restrict__ bias, float* __restrict__ out, int M, int K,
    int N) {
  const int widx = blockIdx.x * 4 + (threadIdx.x >> 6);
  const int lane = threadIdx.x & 63;
  if (widx >= M * N) return;
  const int m = widx / N, n = widx % N;
  const float* a = A + (size_t)m * K;
  const float* w = W + n;
  float s = 0.f;
  for (int k = lane; k < K; k += 64) s += a[k] * w[(size_t)k * N];
#pragma unroll
  for (int off = 32; off; off >>= 1) s += __shfl_xor(s, off);
  if (lane == 0) out[widx] = s + (bias ? bias[n] : 0.f);
}

// ============ layer-batched tiny matmul for the CA chain ====================
__global__ __launch_bounds__(256) void ca_mm_kernel(
    const float* __restrict__ A, size_t a_lstride, const float* __restrict__ W,
    size_t w_lstride, const float* __restrict__ bias, size_t b_lstride,
    float* __restrict__ out, int M, int K, int N) {
  const int widx = blockIdx.x * 4 + (threadIdx.x >> 6);
  const int lane = threadIdx.x & 63;
  if (widx >= L_ * M * N) return;
  const int l = widx / (M * N);
  const int r = widx % (M * N);
  const int m = r / N, n = r % N;
  const float* a = A + l * a_lstride + (size_t)m * K;
  const float* w = W + l * w_lstride + n;
  float s = 0.f;
  for (int k = lane; k < K; k += 64) s += a[k] * w[(size_t)k * N];
#pragma unroll
  for (int off = 32; off; off >>= 1) s += __shfl_xor(s, off);
  if (lane == 0) out[widx] = s + bias[l * b_lstride + n];
}

// ============ MFMA flash attention, work-balanced grid + defer-max ==========
// Q pre-scaled by 1/8 in the qkv GEMM epilogue (exact: exponent shift).
__global__ __launch_bounds__(256) void flash_attn_kernel(
    const short* __restrict__ qkv, short* __restrict__ y) {
  __shared__ short Ks[2][64 * 64];  // [s][d] bf16, swizzled
  __shared__ short Vt[2][64 * 64];  // [d][s] bf16, swizzled
  __shared__ short Ps[4][16 * 64];  // per-wave [t][s] bf16, swizzled
  const int b = blockIdx.x;
  const int pair = b & 255, half = b >> 8;
  const int n = pair >> 5;        // 0..7
  const int h = (pair >> 2) & 7;  // 0..7
  const int tp = pair & 3;        // 0..3
  const int tile = half ? 7 - tp : tp;
  const int t0 = tile * 64;
  const int tid = threadIdx.x, lane = tid & 63, w = tid >> 6;
  const int lhi = lane >> 4, llo = lane & 15;
  char* PsB = (char*)Ps[w];

  const short* qrow = qkv + (size_t)(n * T_ + t0 + w * 16 + llo) * 1536 + h * 64;
  short8 qf[2];
#pragma unroll
  for (int kc = 0; kc < 2; ++kc) qf[kc] = *(const short8*)(qrow + kc * 32 + lhi * 8);

  float m = -1e30f, l = 0.f;
  f32x4 acc[4];
#pragma unroll
  for (int dc = 0; dc < 4; ++dc) acc[dc] = (f32x4)0.f;

  const int arow = lane >> 3;
  const int achunk = ((lane & 7) ^ (lane >> 3)) * 8;  // pre-swizzled chunk
  const int vr = tid >> 2, vd0 = (tid & 3) * 16;      // V-stage assignment
  const int tg = t0 + w * 16 + llo;

  auto stageK = [&](int buf, int s0) {
#pragma unroll
    for (int g = 0; g < 2; ++g) {
      const int r0 = w * 16 + g * 8;
      const short* gp =
          qkv + (size_t)(n * T_ + s0 + r0 + arow) * 1536 + 512 + h * 64 + achunk;
      __builtin_amdgcn_global_load_lds(
          (const __attribute__((address_space(1))) void*)gp,
          (__attribute__((address_space(3))) void*)&Ks[buf][r0 * 64], 16, 0, 0);
    }
  };
  auto loadV = [&](int s0, short8& a, short8& bb) {
    const short* vg = qkv + (size_t)(n * T_ + s0 + vr) * 1536 + 1024 + h * 64 + vd0;
    a = *(const short8*)(vg);
    bb = *(const short8*)(vg + 8);
  };
  auto scatterV = [&](int buf, const short8& a, const short8& bb) {
    char* VtB = (char*)Vt[buf];
#pragma unroll
    for (int j = 0; j < 8; ++j) {
      *(short*)(VtB + swzb(vd0 + j, vr * 2)) = a[j];
      *(short*)(VtB + swzb(vd0 + 8 + j, vr * 2)) = bb[j];
    }
  };

  const int nchunk = tile + 1;
  {
    short8 va, vb;
    stageK(0, 0);
    loadV(0, va, vb);
    scatterV(0, va, vb);
  }
  __syncthreads();

  for (int c = 0; c < nchunk; ++c) {
    const int cur = c & 1;
    const int s0 = c * 64;
    short8 va, vb;
    const bool nxt = (c + 1 < nchunk);
    if (nxt) {  // T14: issue-early
      stageK(cur ^ 1, s0 + 64);
      loadV(s0 + 64, va, vb);
    }
    char* KsB = (char*)Ks[cur];
    char* VtB = (char*)Vt[cur];

    f32x4 st[4];
    __builtin_amdgcn_s_setprio(1);
#pragma unroll
    for (int tle = 0; tle < 4; ++tle) {
      st[tle] = (f32x4)0.f;
#pragma unroll
      for (int kc = 0; kc < 2; ++kc) {
        short8 kf =
            *(const short8*)(KsB + swzb(tle * 16 + llo, kc * 64 + lhi * 16));
        st[tle] =
            __builtin_amdgcn_mfma_f32_16x16x32_bf16(kf, qf[kc], st[tle], 0, 0, 0);
      }
    }
    __builtin_amdgcn_s_setprio(0);
    if (s0 == t0) {  // diagonal chunk: causal mask
#pragma unroll
      for (int tle = 0; tle < 4; ++tle)
#pragma unroll
        for (int r = 0; r < 4; ++r)
          if (s0 + tle * 16 + lhi * 4 + r > tg) st[tle][r] = -1e30f;
    }
    float cmax = -1e30f;
#pragma unroll
    for (int tle = 0; tle < 4; ++tle)
#pragma unroll
      for (int r = 0; r < 4; ++r) cmax = fmaxf(cmax, st[tle][r]);
    cmax = fmaxf(cmax, __shfl_xor(cmax, 16));
    cmax = fmaxf(cmax, __shfl_xor(cmax, 32));
    // T13 defer-max: skip O-rescale when chunk max grew by <= 8 (P <= e^8)
    const bool skip = __all(cmax - m <= 8.f);
    float mn = skip ? m : fmaxf(m, cmax);
    float lsum = 0.f;
#pragma unroll
    for (int tle = 0; tle < 4; ++tle)
#pragma unroll
      for (int r = 0; r < 4; ++r) {
        float p = __expf(st[tle][r] - mn);
        st[tle][r] = p;
        lsum += p;
      }
    lsum += __shfl_xor(lsum, 16);
    lsum += __shfl_xor(lsum, 32);
#pragma unroll
    for (int tle = 0; tle < 4; ++tle) {
      int base = swzb(llo, tle * 32 + lhi * 8);
      *(uint32_t*)(PsB + base) = pack_bf2(st[tle][0], st[tle][1]);
      *(uint32_t*)(PsB + base + 4) = pack_bf2(st[tle][2], st[tle][3]);
    }
    if (skip) {
      l = l + lsum;
    } else {
      float corr = __expf(m - mn);
      l = l * corr + lsum;
      m = mn;
      float c0 = __shfl(corr, lhi * 4 + 0), c1 = __shfl(corr, lhi * 4 + 1);
      float c2 = __shfl(corr, lhi * 4 + 2), c3 = __shfl(corr, lhi * 4 + 3);
#pragma unroll
      for (int dc = 0; dc < 4; ++dc) {
        acc[dc][0] *= c0;
        acc[dc][1] *= c1;
        acc[dc][2] *= c2;
        acc[dc][3] *= c3;
      }
    }
    short8 pf0 = *(const short8*)(PsB + swzb(llo, lhi * 16));
    short8 pf1 = *(const short8*)(PsB + swzb(llo, 64 + lhi * 16));
    __builtin_amdgcn_s_setprio(1);
#pragma unroll
    for (int dc = 0; dc < 4; ++dc) {
      short8 vf0 = *(const short8*)(VtB + swzb(dc * 16 + llo, lhi * 16));
      short8 vf1 = *(const short8*)(VtB + swzb(dc * 16 + llo, 64 + lhi * 16));
      acc[dc] = __builtin_amdgcn_mfma_f32_16x16x32_bf16(pf0, vf0, acc[dc], 0, 0, 0);
      acc[dc] = __builtin_amdgcn_mfma_f32_16x16x32_bf16(pf1, vf1, acc[dc], 0, 0, 0);
    }
    __builtin_amdgcn_s_setprio(0);
    if (nxt) scatterV(cur ^ 1, va, vb);  // T14: write-late (other buffer)
    __syncthreads();
  }

  float linv = 1.f / l;
  float l0 = __shfl(linv, lhi * 4 + 0), l1 = __shfl(linv, lhi * 4 + 1);
  float l2 = __shfl(linv, lhi * 4 + 2), l3 = __shfl(linv, lhi * 4 + 3);
  short* yb = y + (size_t)(n * T_ + t0 + w * 16) * D_ + h * 64;
#pragma unroll
  for (int dc = 0; dc < 4; ++dc) {
    yb[(size_t)(lhi * 4 + 0) * D_ + dc * 16 + llo] = f2bf(acc[dc][0] * l0);
    yb[(size_t)(lhi * 4 + 1) * D_ + dc * 16 + llo] = f2bf(acc[dc][1] * l1);
    yb[(size_t)(lhi * 4 + 2) * D_ + dc * 16 + llo] = f2bf(acc[dc][2] * l2);
    yb[(size_t)(lhi * 4 + 3) * D_ + dc * 16 + llo] = f2bf(acc[dc][3] * l3);
  }
}

// ============ wave-per-row LN: block = 4 waves = 4 rows, no barriers ========
__global__ __launch_bounds__(256) void ln_res_kernel(
    short* __restrict__ xb, const short* __restrict__ res,
    const float* __restrict__ g, const float* __restrict__ b) {
  const int row = blockIdx.x * 4 + (threadIdx.x >> 6);
  const int lane = threadIdx.x & 63;
  const int d0 = lane * 8;
  uint4 xp = *(const uint4*)(xb + (size_t)row * D_ + d0);
  uint4 rp = *(const uint4*)(res + (size_t)row * D_ + d0);
  float xv[8], rv[8], v[8];
  unp8(xp, xv);
  unp8(rp, rv);
  float s = 0.f, sq = 0.f;
#pragma unroll
  for (int i = 0; i < 8; ++i) {
    v[i] = xv[i] + rv[i];
    s += v[i];
    sq += v[i] * v[i];
  }
#pragma unroll
  for (int off = 32; off; off >>= 1) {
    s += __shfl_xor(s, off);
    sq += __shfl_xor(sq, off);
  }
  float mu = s * (1.f / D_);
  float var = sq * (1.f / D_) - mu * mu;
  float r = rsqrtf(var + 1e-5f);
  float4 g0 = *(const float4*)(g + d0), g1 = *(const float4*)(g + d0 + 4);
  float4 b0 = *(const float4*)(b + d0), b1 = *(const float4*)(b + d0 + 4);
  float gg[8] = {g0.x, g0.y, g0.z, g0.w, g1.x, g1.y, g1.z, g1.w};
  float bb[8] = {b0.x, b0.y, b0.z, b0.w, b1.x, b1.y, b1.z, b1.w};
  float o[8];
#pragma unroll
  for (int i = 0; i < 8; ++i) o[i] = (v[i] - mu) * r * gg[i] + bb[i];
  uint4 op = {pack_bf2(o[0], o[1]), pack_bf2(o[2], o[3]),
              pack_bf2(o[4], o[5]), pack_bf2(o[6], o[7])};
  *(uint4*)(xb + (size_t)row * D_ + d0) = op;
}

// ============ wave-per-row DOUBLE LN: xb = LN2(LN1(xb+res) + oc[row/T]) =====
__global__ __launch_bounds__(256) void ln2_res_kernel(
    short* __restrict__ xb, const short* __restrict__ res,
    const float* __restrict__ oc, const float* __restrict__ g1,
    const float* __restrict__ b1, const float* __restrict__ g2,
    const float* __restrict__ b2) {
  const int row = blockIdx.x * 4 + (threadIdx.x >> 6);
  const int lane = threadIdx.x & 63;
  const int d0 = lane * 8;
  uint4 xp = *(const uint4*)(xb + (size_t)row * D_ + d0);
  uint4 rp = *(const uint4*)(res + (size_t)row * D_ + d0);
  float xv[8], rv[8], v[8];
  unp8(xp, xv);
  unp8(rp, rv);
  float s = 0.f, sq = 0.f;
#pragma unroll
  for (int i = 0; i < 8; ++i) {
    v[i] = xv[i] + rv[i];
    s += v[i];
    sq += v[i] * v[i];
  }
#pragma unroll
  for (int off = 32; off; off >>= 1) {
    s += __shfl_xor(s, off);
    sq += __shfl_xor(sq, off);
  }
  float mu = s * (1.f / D_);
  float var = sq * (1.f / D_) - mu * mu;
  float r = rsqrtf(var + 1e-5f);
  float4 ga = *(const float4*)(g1 + d0), gb = *(const float4*)(g1 + d0 + 4);
  float4 ba = *(const float4*)(b1 + d0), bbv = *(const float4*)(b1 + d0 + 4);
  const float* ocr = oc + (size_t)(row / T_) * D_ + d0;
  float4 oa = *(const float4*)(ocr), ob = *(const float4*)(ocr + 4);
  float g1v[8] = {ga.x, ga.y, ga.z, ga.w, gb.x, gb.y, gb.z, gb.w};
  float b1v[8] = {ba.x, ba.y, ba.z, ba.w, bbv.x, bbv.y, bbv.z, bbv.w};
  float ov[8] = {oa.x, oa.y, oa.z, oa.w, ob.x, ob.y, ob.z, ob.w};
  float u[8];
  float s2 = 0.f, sq2 = 0.f;
#pragma unroll
  for (int i = 0; i < 8; ++i) {
    u[i] = (v[i] - mu) * r * g1v[i] + b1v[i] + ov[i];
    s2 += u[i];
    sq2 += u[i] * u[i];
  }
#pragma unroll
  for (int off = 32; off; off >>= 1) {
    s2 += __shfl_xor(s2, off);
    sq2 += __shfl_xor(sq2, off);
  }
  float mu2 = s2 * (1.f / D_);
  float var2 = sq2 * (1.f / D_) - mu2 * mu2;
  float r2 = rsqrtf(var2 + 1e-5f);
  float4 gc = *(const float4*)(g2 + d0), gd = *(const float4*)(g2 + d0 + 4);
  float4 bc = *(const float4*)(b2 + d0), bd = *(const float4*)(b2 + d0 + 4);
  float g2v[8] = {gc.x, gc.y, gc.z, gc.w, gd.x, gd.y, gd.z, gd.w};
  float b2v[8] = {bc.x, bc.y, bc.z, bc.w, bd.x, bd.y, bd.z, bd.w};
  float o[8];
#pragma unroll
  for (int i = 0; i < 8; ++i) o[i] = (u[i] - mu2) * r2 * g2v[i] + b2v[i];
  uint4 op = {pack_bf2(o[0], o[1]), pack_bf2(o[2], o[3]),
              pack_bf2(o[4], o[5]), pack_bf2(o[6], o[7])};
  *(uint4*)(xb + (size_t)row * D_ + d0) = op;
}

// ============ host orchestration ============================================
extern "C" void kernel_launch(void* const* d_in, const int* in_sizes, int n_in,
                              void* d_out, int out_size, void* d_ws,
                              size_t ws_size, hipStream_t stream) {
  const float* features = (const float*)d_in[0];
  const int* captions = (const int*)d_in[1];
  const float* emb_table = (const float*)d_in[2];
  const float* pos_table = (const float*)d_in[3];
  const float* feat_W = (const float*)d_in[4];
  const float* feat_b = (const float*)d_in[5];
  const float* sa_qkv_W = (const float*)d_in[6];
  const float* sa_qkv_b = (const float*)d_in[7];
  const float* sa_o_W = (const float*)d_in[8];
  const float* sa_o_b = (const float*)d_in[9];
  const float* sa_ln = (const float*)d_in[10];
  const float* ca_qkv_W = (const float*)d_in[11];
  const float* ca_qkv_b = (const float*)d_in[12];
  const float* ca_o_W = (const float*)d_in[13];
  const float* ca_o_b = (const float*)d_in[14];
  const float* ca_ln = (const float*)d_in[15];
  const float* ff_W1 = (const float*)d_in[16];
  const float* ff_b1 = (const float*)d_in[17];
  const float* ff_W2 = (const float*)d_in[18];
  const float* ff_b2 = (const float*)d_in[19];
  const float* ff_ln = (const float*)d_in[20];
  const float* out_W = (const float*)d_in[21];
  const float* out_b = (const float*)d_in[22];

  const int ROWS = N_ * T_;  // 4096
  float* out = (float*)d_out;

  // ---- ws scratch ---------------------------------------------------------
  short* xb = (short*)d_ws;  // ROWS*D bf16 (residual stream)
  float* cond = (float*)(xb + (size_t)ROWS * D_);
  float* vcAll = cond + N_ * D_;                // [L][N][D]
  float* ocAll = vcAll + (size_t)L_ * N_ * D_;  // [L][N][D]
  short* outWt = (short*)(ocAll + (size_t)L_ * N_ * D_);
  size_t ws_need = (size_t)ROWS * D_ * 2 + (1 + 2 * L_) * N_ * D_ * 4 +
                   (size_t)V_ * D_ * 2;
  const bool big_ws = ws_size >= ws_need;

  // ---- d_out scratch (consumed before the final GEMM overwrites) ----------
  short* qkvb = (short*)out;                  // ROWS*1536 bf16
  short* yb = qkvb + (size_t)ROWS * 3 * D_;   // ROWS*D bf16
  short* ffhb = yb + (size_t)ROWS * D_;       // ROWS*F bf16
  short* tmpb = ffhb + (size_t)ROWS * F_;     // ROWS*D bf16
  short* wq = tmpb + (size_t)ROWS * D_;       // L*3*D rows of [D]
  short* wo = wq + (size_t)L_ * 3 * D_ * D_;  // L*D rows of [D]
  short* w1 = wo + (size_t)L_ * D_ * D_;      // L*F rows of [D]
  short* w2 = w1 + (size_t)L_ * F_ * D_;      // L*D rows of [F]

  // ---- ALL weight transposes in one launch --------------------------------
  hipLaunchKernelGGL(batched_transpose_kernel, dim3(big_ws ? 5536 : 1536),
                     dim3(256), 0, stream, sa_qkv_W, sa_o_W, ff_W1, ff_W2,
                     out_W, wq, wo, w1, w2, outWt);

  // ---- cond + CA chain (layer-batched wave matmuls) + embedding -----------
  hipLaunchKernelGGL(wave_mm_kernel, dim3((N_ * D_ + 3) / 4), dim3(256), 0,
                     stream, features, feat_W, feat_b, cond, N_, DIN_, D_);
  hipLaunchKernelGGL(ca_mm_kernel, dim3((L_ * N_ * D_ + 3) / 4), dim3(256), 0,
                     stream, cond, (size_t)0, ca_qkv_W + (size_t)2 * D_ * D_,
                     (size_t)3 * D_ * D_, ca_qkv_b + 2 * D_, (size_t)3 * D_,
                     vcAll, N_, D_, D_);
  hipLaunchKernelGGL(ca_mm_kernel, dim3((L_ * N_ * D_ + 3) / 4), dim3(256), 0,
                     stream, vcAll, (size_t)N_ * D_, ca_o_W, (size_t)D_ * D_,
                     ca_o_b, (size_t)D_, ocAll, N_, D_, D_);
  hipLaunchKernelGGL(embed_kernel, dim3(ROWS * D_ / 1024), dim3(256), 0, stream,
                     captions, emb_table, pos_table, xb);

  for (int l = 0; l < L_; ++l) {
    // fused QKV projection (Q pre-scaled by 1/8 in epilogue) -> bf16
    hipLaunchKernelGGL(
        (bf16_gemm_kernel<128, 128, false, true, true, 0, false>),
        dim3(3 * D_ / 128, ROWS / 128), dim3(256), 0, stream, xb,
        wq + (size_t)l * 3 * D_ * D_, sa_qkv_b + (size_t)l * 3 * D_, qkvb,
        ROWS, 3 * D_, D_);
    hipLaunchKernelGGL(flash_attn_kernel, dim3(512), dim3(256), 0, stream,
                       qkvb, yb);
    // attn out projection (N=512, full-coverage 64x128 tile) -> bf16 tmp
    hipLaunchKernelGGL(
        (bf16_gemm_kernel<64, 128, false, true, false, 0, false>),
        dim3(D_ / 128, ROWS / 64), dim3(128), 0, stream, yb,
        wo + (size_t)l * D_ * D_, sa_o_b + (size_t)l * D_, tmpb, ROWS, D_, D_);
    // fused sa-LN + ca-residual + ca-LN (wave-per-row)
    hipLaunchKernelGGL(ln2_res_kernel, dim3(ROWS / 4), dim3(256), 0, stream,
                       xb, tmpb, ocAll + (size_t)l * N_ * D_,
                       sa_ln + (size_t)l * 2 * D_,
                       sa_ln + (size_t)l * 2 * D_ + D_,
                       ca_ln + (size_t)l * 2 * D_,
                       ca_ln + (size_t)l * 2 * D_ + D_);

    // FFN
    hipLaunchKernelGGL(
        (bf16_gemm_kernel<128, 128, true, true, false, 0, false>),
        dim3(F_ / 128, ROWS / 128), dim3(256), 0, stream, xb,
        w1 + (size_t)l * F_ * D_, ff_b1 + (size_t)l * F_, ffhb, ROWS, F_, D_);
    hipLaunchKernelGGL(
        (bf16_gemm_kernel<64, 128, false, true, false, 0, false>),
        dim3(D_ / 128, ROWS / 64), dim3(128), 0, stream, ffhb,
        w2 + (size_t)l * D_ * F_, ff_b2 + (size_t)l * D_, tmpb, ROWS, D_, F_);
    hipLaunchKernelGGL(ln_res_kernel, dim3(ROWS / 4), dim3(256), 0, stream, xb,
                       tmpb, ff_ln + (size_t)l * 2 * D_,
                       ff_ln + (size_t)l * 2 * D_ + D_);
  }

  // ---- final vocab projection: 128^2 tile, bm-fast XCD order, NT stores ---
  if (big_ws) {
    hipLaunchKernelGGL(
        (bf16_gemm_kernel<128, 128, false, false, false, 1, true>),
        dim3(V_ / 128, ROWS / 128), dim3(256), 0, stream, xb, outWt, out_b,
        out, ROWS, V_, D_);
  } else {
    dim3 grid(V_ / 64, ROWS / 128);
    hipLaunchKernelGGL((gemm_f32_kernel<128, 64, 16, 8, 4>), grid, dim3(256), 0,
                       stream, xb, out_W, out_b, out, ROWS, V_, D_);
  }
}

// Round 14
// 444.988 us; speedup vs baseline: 1.1248x; 1.0603x over previous
//
#include <hip/hip_runtime.h>
#include <math.h>
#include <stdint.h>

#define N_ 8
#define T_ 512
#define V_ 32000
#define D_ 512
#define DIN_ 1024
#define H_ 8
#define HD_ 64
#define L_ 2
#define F_ 2048

typedef __attribute__((ext_vector_type(8))) short short8;
typedef __attribute__((ext_vector_type(4))) float f32x4;

__device__ __forceinline__ short f2bf(float f) {
  uint32_t u = __builtin_bit_cast(uint32_t, f);
  u = (u + 0x7FFFu + ((u >> 16) & 1u)) >> 16;
  return (short)u;
}
__device__ __forceinline__ uint32_t pack_bf2(float a, float b) {
  return (uint32_t)(uint16_t)f2bf(a) | ((uint32_t)(uint16_t)f2bf(b) << 16);
}
__device__ __forceinline__ float bflo(uint32_t u) {
  return __builtin_bit_cast(float, u << 16);
}
__device__ __forceinline__ float bfhi(uint32_t u) {
  return __builtin_bit_cast(float, u & 0xffff0000u);
}
__device__ __forceinline__ float bf2f(short s) {
  return __builtin_bit_cast(float, ((uint32_t)(uint16_t)s) << 16);
}
__device__ __forceinline__ void unp8(uint4 p, float* v) {
  v[0] = bflo(p.x); v[1] = bfhi(p.x); v[2] = bflo(p.y); v[3] = bfhi(p.y);
  v[4] = bflo(p.z); v[5] = bfhi(p.z); v[6] = bflo(p.w); v[7] = bfhi(p.w);
}
// XOR-swizzled byte offset within a [row][128B] LDS tile (G4 conflict fix)
__device__ __forceinline__ int swzb(int row, int byteoff) {
  return row * 128 + (byteoff ^ ((row & 7) << 4));
}

// ============ batched transpose + f32->bf16 for ALL weights (one launch) ====
// tile ranges: [0,384) sa_qkv | [384,512) sa_o | [512,1024) ff1 |
// [1024,1536) ff2 | [1536,1664) ca_Wv | [1664,1792) ca_Wo |
// [1792,1920) feat_W | [1920,5920) out_W (big_ws only)
__global__ __launch_bounds__(256) void batched_transpose_kernel(
    const float* __restrict__ sa_qkv_W, const float* __restrict__ sa_o_W,
    const float* __restrict__ ff_W1, const float* __restrict__ ff_W2,
    const float* __restrict__ ca_qkv_W, const float* __restrict__ ca_o_W,
    const float* __restrict__ feat_W, const float* __restrict__ out_W,
    short* __restrict__ wq, short* __restrict__ wo, short* __restrict__ w1,
    short* __restrict__ w2, short* __restrict__ wv, short* __restrict__ woc,
    short* __restrict__ wf, short* __restrict__ outWt) {
  __shared__ float tile[64][65];
  const int t = blockIdx.x;
  const float* src;
  short* dst;
  int K, N, rem;
  if (t < 384) {  // sa_qkv_W: 6 mats [512][512]
    int mat = t >> 6;
    rem = t & 63;
    K = D_; N = D_;
    src = sa_qkv_W + (size_t)mat * D_ * D_;
    dst = wq + (size_t)mat * D_ * D_;
  } else if (t < 512) {  // sa_o_W: 2 mats [512][512]
    int lt = t - 384, mat = lt >> 6;
    rem = lt & 63;
    K = D_; N = D_;
    src = sa_o_W + (size_t)mat * D_ * D_;
    dst = wo + (size_t)mat * D_ * D_;
  } else if (t < 1024) {  // ff_W1: 2 mats [512][2048]
    int lt = t - 512, mat = lt >> 8;
    rem = lt & 255;
    K = D_; N = F_;
    src = ff_W1 + (size_t)mat * D_ * F_;
    dst = w1 + (size_t)mat * F_ * D_;
  } else if (t < 1536) {  // ff_W2: 2 mats [2048][512]
    int lt = t - 1024, mat = lt >> 8;
    rem = lt & 255;
    K = F_; N = D_;
    src = ff_W2 + (size_t)mat * F_ * D_;
    dst = w2 + (size_t)mat * D_ * F_;
  } else if (t < 1664) {  // ca Wv: 2 mats [512][512] at (l*3+2)
    int lt = t - 1536, mat = lt >> 6;
    rem = lt & 63;
    K = D_; N = D_;
    src = ca_qkv_W + (size_t)(mat * 3 + 2) * D_ * D_;
    dst = wv + (size_t)mat * D_ * D_;
  } else if (t < 1792) {  // ca Wo: 2 mats [512][512]
    int lt = t - 1664, mat = lt >> 6;
    rem = lt & 63;
    K = D_; N = D_;
    src = ca_o_W + (size_t)mat * D_ * D_;
    dst = woc + (size_t)mat * D_ * D_;
  } else if (t < 1920) {  // feat_W: [1024][512]
    rem = t - 1792;
    K = DIN_; N = D_;
    src = feat_W;
    dst = wf;
  } else {  // out_W: [512][32000]
    rem = t - 1920;
    K = D_; N = V_;
    src = out_W;
    dst = outWt;
  }
  const int nx = N >> 6;
  const int n0 = (rem % nx) * 64, k0 = (rem / nx) * 64;
  const int tid = threadIdx.x;
  const int c = tid & 63, r4 = tid >> 6;
#pragma unroll
  for (int i = 0; i < 16; ++i) {
    int k = r4 + i * 4;
    tile[k][c] = src[(size_t)(k0 + k) * N + n0 + c];
  }
  __syncthreads();
#pragma unroll
  for (int i = 0; i < 16; ++i) {
    int n = r4 + i * 4;
    dst[(size_t)(n0 + n) * K + k0 + c] = f2bf(tile[c][n]);
  }
}

// ============ bf16 MFMA GEMM (single-buffer m97 structure, runtime K) =======
// C[M,N] = A[M,K](bf16) @ Bt[N,K](bf16)^T + bias. BK=64.
// ORDER 0: row-major XCD chunks; ORDER 1: bm-fast (vocab — B streamed once).
// NT: non-temporal C stores. QS: scale cols<512 by 0.125 (fold Q-scale).
template <int BM, int BN, bool RELU, bool OUTBF, bool QS, int ORDER, bool NT>
__global__ __launch_bounds__((BM / 64) * (BN / 64) * 64) void bf16_gemm_kernel(
    const short* __restrict__ A, const short* __restrict__ Bt,
    const float* __restrict__ bias, void* __restrict__ Cv, int M, int N,
    int K) {
  constexpr int WM = BM / 64, WN = BN / 64, NW = WM * WN;
  constexpr int AISS = BM / (NW * 8), BISS = BN / (NW * 8);
  __shared__ short As[BM * 64];
  __shared__ short Bs[BN * 64];
  const int tid = threadIdx.x, lane = tid & 63, w = tid >> 6;
  const int wr = w / WN, wc = w % WN;
  const int lhi = lane >> 4, llo = lane & 15;

  const int gx = gridDim.x, gy = gridDim.y;
  const int nwg = gx * gy;
  int lin = blockIdx.y * gx + blockIdx.x;
  if ((nwg & 7) == 0) lin = (lin & 7) * (nwg >> 3) + (lin >> 3);
  int bm, bn;
  if (ORDER == 1) {
    bm = (lin % gy) * BM;
    bn = (lin / gy) * BN;
  } else {
    bm = (lin / gx) * BM;
    bn = (lin % gx) * BN;
  }

  const int arow = lane >> 3;                         // row within 8-row issue
  const int achunk = ((lane & 7) ^ (lane >> 3)) * 8;  // pre-swizzled k-chunk

  f32x4 acc[4][4];
#pragma unroll
  for (int i = 0; i < 4; ++i)
#pragma unroll
    for (int j = 0; j < 4; ++j) acc[i][j] = (f32x4)0.f;

  char* AsB = (char*)As;
  char* BsB = (char*)Bs;

  for (int k0 = 0; k0 < K; k0 += 64) {
#pragma unroll
    for (int g = 0; g < AISS; ++g) {
      const int r0 = (w * AISS + g) * 8;
      const short* gp = A + (size_t)(bm + r0 + arow) * K + k0 + achunk;
      __builtin_amdgcn_global_load_lds(
          (const __attribute__((address_space(1))) void*)gp,
          (__attribute__((address_space(3))) void*)&As[r0 * 64], 16, 0, 0);
    }
#pragma unroll
    for (int g = 0; g < BISS; ++g) {
      const int r0 = (w * BISS + g) * 8;
      const short* gp = Bt + (size_t)(bn + r0 + arow) * K + k0 + achunk;
      __builtin_amdgcn_global_load_lds(
          (const __attribute__((address_space(1))) void*)gp,
          (__attribute__((address_space(3))) void*)&Bs[r0 * 64], 16, 0, 0);
    }
    __syncthreads();
#pragma unroll
    for (int ks = 0; ks < 2; ++ks) {
      short8 af[4], bf[4];
#pragma unroll
      for (int i = 0; i < 4; ++i)
        af[i] = *(const short8*)(AsB + swzb(wr * 64 + i * 16 + llo,
                                            ks * 64 + lhi * 16));
#pragma unroll
      for (int j = 0; j < 4; ++j)
        bf[j] = *(const short8*)(BsB + swzb(wc * 64 + j * 16 + llo,
                                            ks * 64 + lhi * 16));
#pragma unroll
      for (int i = 0; i < 4; ++i)
#pragma unroll
        for (int j = 0; j < 4; ++j)
          acc[i][j] = __builtin_amdgcn_mfma_f32_16x16x32_bf16(af[i], bf[j],
                                                              acc[i][j], 0, 0, 0);
    }
    __syncthreads();
  }
  // epilogue: C/D layout col=lane&15, row=(lane>>4)*4+r
#pragma unroll
  for (int j = 0; j < 4; ++j) {
    const int col = bn + wc * 64 + j * 16 + llo;
    const float bv = bias ? bias[col] : 0.f;
    const float scl = (QS && col < 512) ? 0.125f : 1.f;
#pragma unroll
    for (int i = 0; i < 4; ++i) {
      const int row0 = bm + wr * 64 + i * 16 + lhi * 4;
#pragma unroll
      for (int r = 0; r < 4; ++r) {
        float v = acc[i][j][r] + bv;
        if (RELU) v = fmaxf(v, 0.f);
        if (QS) v *= scl;
        if (OUTBF) {
          ((short*)Cv)[(size_t)(row0 + r) * N + col] = f2bf(v);
        } else if (NT) {
          __builtin_nontemporal_store(v, &((float*)Cv)[(size_t)(row0 + r) * N + col]);
        } else {
          ((float*)Cv)[(size_t)(row0 + r) * N + col] = v;
        }
      }
    }
  }
}

// ============ fallback f32 SIMT GEMM (bf16 A; only if ws too small) =========
template <int BM, int BN, int BK, int TM, int TN>
__global__ __launch_bounds__((BM / TM) * (BN / TN)) void gemm_f32_kernel(
    const short* __restrict__ A, const float* __restrict__ B,
    const float* __restrict__ bias, float* __restrict__ C, int M, int N,
    int K) {
  constexpr int THREADS = (BM / TM) * (BN / TN);
  __shared__ float As[BK][BM + 1];
  __shared__ float Bs[BK][BN + 1];
  const int tid = threadIdx.x;
  const int bm = blockIdx.y * BM, bn = blockIdx.x * BN;
  const int tcol = tid % (BN / TN), trow = tid / (BN / TN);
  float acc[TM][TN];
#pragma unroll
  for (int i = 0; i < TM; ++i)
#pragma unroll
    for (int j = 0; j < TN; ++j) acc[i][j] = 0.f;
  for (int k0 = 0; k0 < K; k0 += BK) {
    for (int i = tid; i < BM * BK; i += THREADS) {
      int m = i / BK, kk = i % BK;
      As[kk][m] = bf2f(A[(size_t)(bm + m) * K + (k0 + kk)]);
    }
    for (int i = tid; i < BK * BN; i += THREADS) {
      int kk = i / BN, n = i % BN;
      Bs[kk][n] = B[(size_t)(k0 + kk) * N + (bn + n)];
    }
    __syncthreads();
#pragma unroll
    for (int kk = 0; kk < BK; ++kk) {
      float a[TM], b[TN];
#pragma unroll
      for (int i = 0; i < TM; ++i) a[i] = As[kk][trow * TM + i];
#pragma unroll
      for (int j = 0; j < TN; ++j) b[j] = Bs[kk][tcol * TN + j];
#pragma unroll
      for (int i = 0; i < TM; ++i)
#pragma unroll
        for (int j = 0; j < TN; ++j) acc[i][j] += a[i] * b[j];
    }
    __syncthreads();
  }
#pragma unroll
  for (int i = 0; i < TM; ++i) {
    int m = bm + trow * TM + i;
#pragma unroll
    for (int j = 0; j < TN; ++j) {
      int n = bn + tcol * TN + j;
      C[(size_t)m * N + n] = acc[i][j] + (bias ? bias[n] : 0.f);
    }
  }
}

// ============ token + positional embedding (bf16 out only) ==================
__global__ __launch_bounds__(256) void embed_kernel(
    const int* __restrict__ captions, const float* __restrict__ emb,
    const float* __restrict__ pos, short* __restrict__ xb) {
  int idx4 = (blockIdx.x * 256 + threadIdx.x) * 4;  // over N*T*D
  int d = idx4 % D_;
  int nt = idx4 / D_;
  int t = nt % T_;
  int tok = captions[nt];
  float4 e = *(const float4*)(emb + (size_t)tok * D_ + d);
  float4 p = *(const float4*)(pos + (size_t)t * D_ + d);
  *(uint32_t*)(xb + idx4) = pack_bf2(e.x + p.x, e.y + p.y);
  *(uint32_t*)(xb + idx4 + 2) = pack_bf2(e.z + p.z, e.w + p.w);
}

// ============ tiny matmul vs TRANSPOSED bf16 weights (coalesced) ============
// out[l][m][n] = A[l*a_ls + m*K :] . WT[l*w_ls + n*K :] + bias[l*b_ls + n]
// one wave per output; lane covers k = lane*8 .. (vectorized short8/float4)
__global__ __launch_bounds__(256) void tiny_mmT_kernel(
    const float* __restrict__ A, size_t a_ls, const short* __restrict__ WT,
    size_t w_ls, const float* __restrict__ bias, size_t b_ls,
    float* __restrict__ out, int NL, int M, int K, int N) {
  const int widx = blockIdx.x * 4 + (threadIdx.x >> 6);
  const int lane = threadIdx.x & 63;
  if (widx >= NL * M * N) return;
  const int l = widx / (M * N);
  const int r = widx % (M * N);
  const int m = r / N, n = r % N;
  const float* a = A + l * a_ls + (size_t)m * K;
  const short* wt = WT + l * w_ls + (size_t)n * K;
  float s = 0.f;
  for (int k = lane * 8; k < K; k += 512) {
    float4 a0 = *(const float4*)(a + k);
    float4 a1 = *(const float4*)(a + k + 4);
    short8 wv = *(const short8*)(wt + k);
    s += a0.x * bf2f(wv[0]) + a0.y * bf2f(wv[1]) + a0.z * bf2f(wv[2]) +
         a0.w * bf2f(wv[3]) + a1.x * bf2f(wv[4]) + a1.y * bf2f(wv[5]) +
         a1.z * bf2f(wv[6]) + a1.w * bf2f(wv[7]);
  }
#pragma unroll
  for (int off = 32; off; off >>= 1) s += __shfl_xor(s, off);
  if (lane == 0) out[widx] = s + bias[l * b_ls + n];
}

// ============ MFMA flash attention, work-balanced grid + defer-max ==========
// Q pre-scaled by 1/8 in the qkv GEMM epilogue (exact: exponent shift).
__global__ __launch_bounds__(256) void flash_attn_kernel(
    const short* __restrict__ qkv, short* __restrict__ y) {
  __shared__ short Ks[2][64 * 64];  // [s][d] bf16, swizzled
  __shared__ short Vt[2][64 * 64];  // [d][s] bf16, swizzled
  __shared__ short Ps[4][16 * 64];  // per-wave [t][s] bf16, swizzled
  const int b = blockIdx.x;
  const int pair = b & 255, half = b >> 8;
  const int n = pair >> 5;        // 0..7
  const int h = (pair >> 2) & 7;  // 0..7
  const int tp = pair & 3;        // 0..3
  const int tile = half ? 7 - tp : tp;
  const int t0 = tile * 64;
  const int tid = threadIdx.x, lane = tid & 63, w = tid >> 6;
  const int lhi = lane >> 4, llo = lane & 15;
  char* PsB = (char*)Ps[w];

  const short* qrow = qkv + (size_t)(n * T_ + t0 + w * 16 + llo) * 1536 + h * 64;
  short8 qf[2];
#pragma unroll
  for (int kc = 0; kc < 2; ++kc) qf[kc] = *(const short8*)(qrow + kc * 32 + lhi * 8);

  float m = -1e30f, l = 0.f;
  f32x4 acc[4];
#pragma unroll
  for (int dc = 0; dc < 4; ++dc) acc[dc] = (f32x4)0.f;

  const int arow = lane >> 3;
  const int achunk = ((lane & 7) ^ (lane >> 3)) * 8;  // pre-swizzled chunk
  const int vr = tid >> 2, vd0 = (tid & 3) * 16;      // V-stage assignment
  const int tg = t0 + w * 16 + llo;

  auto stageK = [&](int buf, int s0) {
#pragma unroll
    for (int g = 0; g < 2; ++g) {
      const int r0 = w * 16 + g * 8;
      const short* gp =
          qkv + (size_t)(n * T_ + s0 + r0 + arow) * 1536 + 512 + h * 64 + achunk;
      __builtin_amdgcn_global_load_lds(
          (const __attribute__((address_space(1))) void*)gp,
          (__attribute__((address_space(3))) void*)&Ks[buf][r0 * 64], 16, 0, 0);
    }
  };
  auto loadV = [&](int s0, short8& a, short8& bb) {
    const short* vg = qkv + (size_t)(n * T_ + s0 + vr) * 1536 + 1024 + h * 64 + vd0;
    a = *(const short8*)(vg);
    bb = *(const short8*)(vg + 8);
  };
  auto scatterV = [&](int buf, const short8& a, const short8& bb) {
    char* VtB = (char*)Vt[buf];
#pragma unroll
    for (int j = 0; j < 8; ++j) {
      *(short*)(VtB + swzb(vd0 + j, vr * 2)) = a[j];
      *(short*)(VtB + swzb(vd0 + 8 + j, vr * 2)) = bb[j];
    }
  };

  const int nchunk = tile + 1;
  {
    short8 va, vb;
    stageK(0, 0);
    loadV(0, va, vb);
    scatterV(0, va, vb);
  }
  __syncthreads();

  for (int c = 0; c < nchunk; ++c) {
    const int cur = c & 1;
    const int s0 = c * 64;
    short8 va, vb;
    const bool nxt = (c + 1 < nchunk);
    if (nxt) {  // T14: issue-early
      stageK(cur ^ 1, s0 + 64);
      loadV(s0 + 64, va, vb);
    }
    char* KsB = (char*)Ks[cur];
    char* VtB = (char*)Vt[cur];

    f32x4 st[4];
    __builtin_amdgcn_s_setprio(1);
#pragma unroll
    for (int tle = 0; tle < 4; ++tle) {
      st[tle] = (f32x4)0.f;
#pragma unroll
      for (int kc = 0; kc < 2; ++kc) {
        short8 kf =
            *(const short8*)(KsB + swzb(tle * 16 + llo, kc * 64 + lhi * 16));
        st[tle] =
            __builtin_amdgcn_mfma_f32_16x16x32_bf16(kf, qf[kc], st[tle], 0, 0, 0);
      }
    }
    __builtin_amdgcn_s_setprio(0);
    if (s0 == t0) {  // diagonal chunk: causal mask
#pragma unroll
      for (int tle = 0; tle < 4; ++tle)
#pragma unroll
        for (int r = 0; r < 4; ++r)
          if (s0 + tle * 16 + lhi * 4 + r > tg) st[tle][r] = -1e30f;
    }
    float cmax = -1e30f;
#pragma unroll
    for (int tle = 0; tle < 4; ++tle)
#pragma unroll
      for (int r = 0; r < 4; ++r) cmax = fmaxf(cmax, st[tle][r]);
    cmax = fmaxf(cmax, __shfl_xor(cmax, 16));
    cmax = fmaxf(cmax, __shfl_xor(cmax, 32));
    // T13 defer-max: skip O-rescale when chunk max grew by <= 8 (P <= e^8)
    const bool skip = __all(cmax - m <= 8.f);
    float mn = skip ? m : fmaxf(m, cmax);
    float lsum = 0.f;
#pragma unroll
    for (int tle = 0; tle < 4; ++tle)
#pragma unroll
      for (int r = 0; r < 4; ++r) {
        float p = __expf(st[tle][r] - mn);
        st[tle][r] = p;
        lsum += p;
      }
    lsum += __shfl_xor(lsum, 16);
    lsum += __shfl_xor(lsum, 32);
#pragma unroll
    for (int tle = 0; tle < 4; ++tle) {
      int base = swzb(llo, tle * 32 + lhi * 8);
      *(uint32_t*)(PsB + base) = pack_bf2(st[tle][0], st[tle][1]);
      *(uint32_t*)(PsB + base + 4) = pack_bf2(st[tle][2], st[tle][3]);
    }
    if (skip) {
      l = l + lsum;
    } else {
      float corr = __expf(m - mn);
      l = l * corr + lsum;
      m = mn;
      float c0 = __shfl(corr, lhi * 4 + 0), c1 = __shfl(corr, lhi * 4 + 1);
      float c2 = __shfl(corr, lhi * 4 + 2), c3 = __shfl(corr, lhi * 4 + 3);
#pragma unroll
      for (int dc = 0; dc < 4; ++dc) {
        acc[dc][0] *= c0;
        acc[dc][1] *= c1;
        acc[dc][2] *= c2;
        acc[dc][3] *= c3;
      }
    }
    short8 pf0 = *(const short8*)(PsB + swzb(llo, lhi * 16));
    short8 pf1 = *(const short8*)(PsB + swzb(llo, 64 + lhi * 16));
    __builtin_amdgcn_s_setprio(1);
#pragma unroll
    for (int dc = 0; dc < 4; ++dc) {
      short8 vf0 = *(const short8*)(VtB + swzb(dc * 16 + llo, lhi * 16));
      short8 vf1 = *(const short8*)(VtB + swzb(dc * 16 + llo, 64 + lhi * 16));
      acc[dc] = __builtin_amdgcn_mfma_f32_16x16x32_bf16(pf0, vf0, acc[dc], 0, 0, 0);
      acc[dc] = __builtin_amdgcn_mfma_f32_16x16x32_bf16(pf1, vf1, acc[dc], 0, 0, 0);
    }
    __builtin_amdgcn_s_setprio(0);
    if (nxt) scatterV(cur ^ 1, va, vb);  // T14: write-late (other buffer)
    __syncthreads();
  }

  float linv = 1.f / l;
  float l0 = __shfl(linv, lhi * 4 + 0), l1 = __shfl(linv, lhi * 4 + 1);
  float l2 = __shfl(linv, lhi * 4 + 2), l3 = __shfl(linv, lhi * 4 + 3);
  short* yb = y + (size_t)(n * T_ + t0 + w * 16) * D_ + h * 64;
#pragma unroll
  for (int dc = 0; dc < 4; ++dc) {
    yb[(size_t)(lhi * 4 + 0) * D_ + dc * 16 + llo] = f2bf(acc[dc][0] * l0);
    yb[(size_t)(lhi * 4 + 1) * D_ + dc * 16 + llo] = f2bf(acc[dc][1] * l1);
    yb[(size_t)(lhi * 4 + 2) * D_ + dc * 16 + llo] = f2bf(acc[dc][2] * l2);
    yb[(size_t)(lhi * 4 + 3) * D_ + dc * 16 + llo] = f2bf(acc[dc][3] * l3);
  }
}

// ============ wave-per-row LN: block = 4 waves = 4 rows, no barriers ========
__global__ __launch_bounds__(256) void ln_res_kernel(
    short* __restrict__ xb, const short* __restrict__ res,
    const float* __restrict__ g, const float* __restrict__ b) {
  const int row = blockIdx.x * 4 + (threadIdx.x >> 6);
  const int lane = threadIdx.x & 63;
  const int d0 = lane * 8;
  uint4 xp = *(const uint4*)(xb + (size_t)row * D_ + d0);
  uint4 rp = *(const uint4*)(res + (size_t)row * D_ + d0);
  float xv[8], rv[8], v[8];
  unp8(xp, xv);
  unp8(rp, rv);
  float s = 0.f, sq = 0.f;
#pragma unroll
  for (int i = 0; i < 8; ++i) {
    v[i] = xv[i] + rv[i];
    s += v[i];
    sq += v[i] * v[i];
  }
#pragma unroll
  for (int off = 32; off; off >>= 1) {
    s += __shfl_xor(s, off);
    sq += __shfl_xor(sq, off);
  }
  float mu = s * (1.f / D_);
  float var = sq * (1.f / D_) - mu * mu;
  float r = rsqrtf(var + 1e-5f);
  float4 g0 = *(const float4*)(g + d0), g1 = *(const float4*)(g + d0 + 4);
  float4 b0 = *(const float4*)(b + d0), b1 = *(const float4*)(b + d0 + 4);
  float gg[8] = {g0.x, g0.y, g0.z, g0.w, g1.x, g1.y, g1.z, g1.w};
  float bb[8] = {b0.x, b0.y, b0.z, b0.w, b1.x, b1.y, b1.z, b1.w};
  float o[8];
#pragma unroll
  for (int i = 0; i < 8; ++i) o[i] = (v[i] - mu) * r * gg[i] + bb[i];
  uint4 op = {pack_bf2(o[0], o[1]), pack_bf2(o[2], o[3]),
              pack_bf2(o[4], o[5]), pack_bf2(o[6], o[7])};
  *(uint4*)(xb + (size_t)row * D_ + d0) = op;
}

// ============ wave-per-row DOUBLE LN: xb = LN2(LN1(xb+res) + oc[row/T]) =====
__global__ __launch_bounds__(256) void ln2_res_kernel(
    short* __restrict__ xb, const short* __restrict__ res,
    const float* __restrict__ oc, const float* __restrict__ g1,
    const float* __restrict__ b1, const float* __restrict__ g2,
    const float* __restrict__ b2) {
  const int row = blockIdx.x * 4 + (threadIdx.x >> 6);
  const int lane = threadIdx.x & 63;
  const int d0 = lane * 8;
  uint4 xp = *(const uint4*)(xb + (size_t)row * D_ + d0);
  uint4 rp = *(const uint4*)(res + (size_t)row * D_ + d0);
  float xv[8], rv[8], v[8];
  unp8(xp, xv);
  unp8(rp, rv);
  float s = 0.f, sq = 0.f;
#pragma unroll
  for (int i = 0; i < 8; ++i) {
    v[i] = xv[i] + rv[i];
    s += v[i];
    sq += v[i] * v[i];
  }
#pragma unroll
  for (int off = 32; off; off >>= 1) {
    s += __shfl_xor(s, off);
    sq += __shfl_xor(sq, off);
  }
  float mu = s * (1.f / D_);
  float var = sq * (1.f / D_) - mu * mu;
  float r = rsqrtf(var + 1e-5f);
  float4 ga = *(const float4*)(g1 + d0), gb = *(const float4*)(g1 + d0 + 4);
  float4 ba = *(const float4*)(b1 + d0), bbv = *(const float4*)(b1 + d0 + 4);
  const float* ocr = oc + (size_t)(row / T_) * D_ + d0;
  float4 oa = *(const float4*)(ocr), ob = *(const float4*)(ocr + 4);
  float g1v[8] = {ga.x, ga.y, ga.z, ga.w, gb.x, gb.y, gb.z, gb.w};
  float b1v[8] = {ba.x, ba.y, ba.z, ba.w, bbv.x, bbv.y, bbv.z, bbv.w};
  float ov[8] = {oa.x, oa.y, oa.z, oa.w, ob.x, ob.y, ob.z, ob.w};
  float u[8];
  float s2 = 0.f, sq2 = 0.f;
#pragma unroll
  for (int i = 0; i < 8; ++i) {
    u[i] = (v[i] - mu) * r * g1v[i] + b1v[i] + ov[i];
    s2 += u[i];
    sq2 += u[i] * u[i];
  }
#pragma unroll
  for (int off = 32; off; off >>= 1) {
    s2 += __shfl_xor(s2, off);
    sq2 += __shfl_xor(sq2, off);
  }
  float mu2 = s2 * (1.f / D_);
  float var2 = sq2 * (1.f / D_) - mu2 * mu2;
  float r2 = rsqrtf(var2 + 1e-5f);
  float4 gc = *(const float4*)(g2 + d0), gd = *(const float4*)(g2 + d0 + 4);
  float4 bc = *(const float4*)(b2 + d0), bd = *(const float4*)(b2 + d0 + 4);
  float g2v[8] = {gc.x, gc.y, gc.z, gc.w, gd.x, gd.y, gd.z, gd.w};
  float b2v[8] = {bc.x, bc.y, bc.z, bc.w, bd.x, bd.y, bd.z, bd.w};
  float o[8];
#pragma unroll
  for (int i = 0; i < 8; ++i) o[i] = (u[i] - mu2) * r2 * g2v[i] + b2v[i];
  uint4 op = {pack_bf2(o[0], o[1]), pack_bf2(o[2], o[3]),
              pack_bf2(o[4], o[5]), pack_bf2(o[6], o[7])};
  *(uint4*)(xb + (size_t)row * D_ + d0) = op;
}

// ============ host orchestration ============================================
extern "C" void kernel_launch(void* const* d_in, const int* in_sizes, int n_in,
                              void* d_out, int out_size, void* d_ws,
                              size_t ws_size, hipStream_t stream) {
  const float* features = (const float*)d_in[0];
  const int* captions = (const int*)d_in[1];
  const float* emb_table = (const float*)d_in[2];
  const float* pos_table = (const float*)d_in[3];
  const float* feat_W = (const float*)d_in[4];
  const float* feat_b = (const float*)d_in[5];
  const float* sa_qkv_W = (const float*)d_in[6];
  const float* sa_qkv_b = (const float*)d_in[7];
  const float* sa_o_W = (const float*)d_in[8];
  const float* sa_o_b = (const float*)d_in[9];
  const float* sa_ln = (const float*)d_in[10];
  const float* ca_qkv_W = (const float*)d_in[11];
  const float* ca_qkv_b = (const float*)d_in[12];
  const float* ca_o_W = (const float*)d_in[13];
  const float* ca_o_b = (const float*)d_in[14];
  const float* ca_ln = (const float*)d_in[15];
  const float* ff_W1 = (const float*)d_in[16];
  const float* ff_b1 = (const float*)d_in[17];
  const float* ff_W2 = (const float*)d_in[18];
  const float* ff_b2 = (const float*)d_in[19];
  const float* ff_ln = (const float*)d_in[20];
  const float* out_W = (const float*)d_in[21];
  const float* out_b = (const float*)d_in[22];

  const int ROWS = N_ * T_;  // 4096
  float* out = (float*)d_out;

  // ---- ws scratch ---------------------------------------------------------
  short* xb = (short*)d_ws;  // ROWS*D bf16 (residual stream)
  float* cond = (float*)(xb + (size_t)ROWS * D_);
  float* vcAll = cond + N_ * D_;                // [L][N][D]
  float* ocAll = vcAll + (size_t)L_ * N_ * D_;  // [L][N][D]
  short* outWt = (short*)(ocAll + (size_t)L_ * N_ * D_);
  size_t ws_need = (size_t)ROWS * D_ * 2 + (1 + 2 * L_) * N_ * D_ * 4 +
                   (size_t)V_ * D_ * 2;
  const bool big_ws = ws_size >= ws_need;

  // ---- d_out scratch (consumed before the final GEMM overwrites) ----------
  short* qkvb = (short*)out;                  // ROWS*1536 bf16
  short* yb = qkvb + (size_t)ROWS * 3 * D_;   // ROWS*D bf16
  short* ffhb = yb + (size_t)ROWS * D_;       // ROWS*F bf16
  short* tmpb = ffhb + (size_t)ROWS * F_;     // ROWS*D bf16
  short* wq = tmpb + (size_t)ROWS * D_;       // L*3*D rows of [D]
  short* wo = wq + (size_t)L_ * 3 * D_ * D_;  // L*D rows of [D]
  short* w1 = wo + (size_t)L_ * D_ * D_;      // L*F rows of [D]
  short* w2 = w1 + (size_t)L_ * F_ * D_;      // L*D rows of [F]
  short* wv = w2 + (size_t)L_ * D_ * F_;      // L*D rows of [D] (ca Wv^T)
  short* woc = wv + (size_t)L_ * D_ * D_;     // L*D rows of [D] (ca Wo^T)
  short* wf = woc + (size_t)L_ * D_ * D_;     // D rows of [DIN] (feat_W^T)

  // ---- ALL weight transposes in one launch --------------------------------
  hipLaunchKernelGGL(batched_transpose_kernel, dim3(big_ws ? 5920 : 1920),
                     dim3(256), 0, stream, sa_qkv_W, sa_o_W, ff_W1, ff_W2,
                     ca_qkv_W, ca_o_W, feat_W, out_W, wq, wo, w1, w2, wv, woc,
                     wf, outWt);

  // ---- cond + CA chain (coalesced bf16-weight tiny matmuls) + embedding ---
  hipLaunchKernelGGL(tiny_mmT_kernel, dim3((N_ * D_ + 3) / 4), dim3(256), 0,
                     stream, features, (size_t)0, wf, (size_t)0, feat_b,
                     (size_t)0, cond, 1, N_, DIN_, D_);
  hipLaunchKernelGGL(tiny_mmT_kernel, dim3((L_ * N_ * D_ + 3) / 4), dim3(256),
                     0, stream, cond, (size_t)0, wv, (size_t)D_ * D_,
                     ca_qkv_b + 2 * D_, (size_t)3 * D_, vcAll, L_, N_, D_, D_);
  hipLaunchKernelGGL(tiny_mmT_kernel, dim3((L_ * N_ * D_ + 3) / 4), dim3(256),
                     0, stream, vcAll, (size_t)N_ * D_, woc, (size_t)D_ * D_,
                     ca_o_b, (size_t)D_, ocAll, L_, N_, D_, D_);
  hipLaunchKernelGGL(embed_kernel, dim3(ROWS * D_ / 1024), dim3(256), 0, stream,
                     captions, emb_table, pos_table, xb);

  for (int l = 0; l < L_; ++l) {
    // fused QKV projection (Q pre-scaled by 1/8 in epilogue) -> bf16
    hipLaunchKernelGGL(
        (bf16_gemm_kernel<128, 128, false, true, true, 0, false>),
        dim3(3 * D_ / 128, ROWS / 128), dim3(256), 0, stream, xb,
        wq + (size_t)l * 3 * D_ * D_, sa_qkv_b + (size_t)l * 3 * D_, qkvb,
        ROWS, 3 * D_, D_);
    hipLaunchKernelGGL(flash_attn_kernel, dim3(512), dim3(256), 0, stream,
                       qkvb, yb);
    // attn out projection (N=512, full-coverage 64x128 tile) -> bf16 tmp
    hipLaunchKernelGGL(
        (bf16_gemm_kernel<64, 128, false, true, false, 0, false>),
        dim3(D_ / 128, ROWS / 64), dim3(128), 0, stream, yb,
        wo + (size_t)l * D_ * D_, sa_o_b + (size_t)l * D_, tmpb, ROWS, D_, D_);
    // fused sa-LN + ca-residual + ca-LN (wave-per-row)
    hipLaunchKernelGGL(ln2_res_kernel, dim3(ROWS / 4), dim3(256), 0, stream,
                       xb, tmpb, ocAll + (size_t)l * N_ * D_,
                       sa_ln + (size_t)l * 2 * D_,
                       sa_ln + (size_t)l * 2 * D_ + D_,
                       ca_ln + (size_t)l * 2 * D_,
                       ca_ln + (size_t)l * 2 * D_ + D_);

    // FFN
    hipLaunchKernelGGL(
        (bf16_gemm_kernel<128, 128, true, true, false, 0, false>),
        dim3(F_ / 128, ROWS / 128), dim3(256), 0, stream, xb,
        w1 + (size_t)l * F_ * D_, ff_b1 + (size_t)l * F_, ffhb, ROWS, F_, D_);
    hipLaunchKernelGGL(
        (bf16_gemm_kernel<64, 128, false, true, false, 0, false>),
        dim3(D_ / 128, ROWS / 64), dim3(128), 0, stream, ffhb,
        w2 + (size_t)l * D_ * F_, ff_b2 + (size_t)l * D_, tmpb, ROWS, D_, F_);
    hipLaunchKernelGGL(ln_res_kernel, dim3(ROWS / 4), dim3(256), 0, stream, xb,
                       tmpb, ff_ln + (size_t)l * 2 * D_,
                       ff_ln + (size_t)l * 2 * D_ + D_);
  }

  // ---- final vocab projection: 128^2 tile, bm-fast XCD order, NT stores ---
  if (big_ws) {
    hipLaunchKernelGGL(
        (bf16_gemm_kernel<128, 128, false, false, false, 1, true>),
        dim3(V_ / 128, ROWS / 128), dim3(256), 0, stream, xb, outWt, out_b,
        out, ROWS, V_, D_);
  } else {
    dim3 grid(V_ / 64, ROWS / 128);
    hipLaunchKernelGGL((gemm_f32_kernel<128, 64, 16, 8, 4>), grid, dim3(256), 0,
                       stream, xb, out_W, out_b, out, ROWS, V_, D_);
  }
}